// Round 1
// baseline (1036.018 us; speedup 1.0000x reference)
//
#include <hip/hip_runtime.h>
#include <math.h>

#define BATCH 4096
#define NF 10
#define TLEN 480
#define NWIN 24
#define WLEN 20
#define HID 64
#define NPAIR 45
#define DIN 210
#define NG 14
#define GATES 192
#define BB 8

// ---------------------------------------------------------------------------
// ws layout:
//   feat  : BATCH*NWIN*DIN floats   (raw stats, laid out as seq[b][t][ch])
//   accum : 2*NG doubles            (group sum, group sumsq)
//   WT    : transposed weights: WihT0[210][192], WhhT0[64][192],
//                               WihT1[64][192],  WhhT1[64][192]
// ---------------------------------------------------------------------------

__global__ void prep_kernel(const float* __restrict__ Wih0, const float* __restrict__ Whh0,
                            const float* __restrict__ Wih1, const float* __restrict__ Whh1,
                            float* __restrict__ WT) {
    int stride = gridDim.x * blockDim.x;
    int idx = blockIdx.x * blockDim.x + threadIdx.x;
    float* T0 = WT;                    // [210][192]
    float* T1 = WT + DIN * GATES;      // [64][192]
    float* T2 = T1 + HID * GATES;      // [64][192]
    float* T3 = T2 + HID * GATES;      // [64][192]
    for (int i = idx; i < GATES * DIN; i += stride) { int g = i / DIN, k = i % DIN; T0[k * GATES + g] = Wih0[i]; }
    for (int i = idx; i < GATES * HID; i += stride) { int g = i / HID, k = i % HID; T1[k * GATES + g] = Whh0[i]; }
    for (int i = idx; i < GATES * HID; i += stride) { int g = i / HID, k = i % HID; T2[k * GATES + g] = Wih1[i]; }
    for (int i = idx; i < GATES * HID; i += stride) { int g = i / HID, k = i % HID; T3[k * GATES + g] = Whh1[i]; }
}

// One block per batch element. 256 threads.
__global__ __launch_bounds__(256)
void stats_kernel(const float* __restrict__ data,
                  const int* __restrict__ comb_a,
                  const int* __restrict__ comb_b,
                  float* __restrict__ feat) {
    __shared__ float xs[NF * TLEN];        // 19200 B
    __shared__ float mean_s[NF * NWIN];
    __shared__ float std_s[NF * NWIN];
    int b = blockIdx.x;
    int tid = threadIdx.x;
    const float* src = data + (size_t)b * (NF * TLEN);
    for (int i = tid; i < NF * TLEN; i += 256) xs[i] = src[i];
    __syncthreads();

    if (tid < NF * NWIN) {
        int f = tid / NWIN, nw = tid % NWIN;
        float v[WLEN];
        const float* p = &xs[f * TLEN + nw * WLEN];
        #pragma unroll
        for (int t = 0; t < WLEN; ++t) v[t] = p[t];

        float sum = 0.f, minv = v[0], wsum = 0.f;
        #pragma unroll
        for (int t = 0; t < WLEN; ++t) {
            sum += v[t];
            minv = fminf(minv, v[t]);
            wsum += v[t] * ((float)(t + 1) * (1.0f / 210.0f));
        }
        float mean = sum * (1.0f / WLEN);
        float var = 0.f, m3 = 0.f, m4 = 0.f;
        #pragma unroll
        for (int t = 0; t < WLEN; ++t) {
            float c = v[t] - mean;
            float c2 = c * c;
            var += c2; m3 += c2 * c; m4 += c2 * c2;
        }
        var *= (1.0f / WLEN); m3 *= (1.0f / WLEN); m4 *= (1.0f / WLEN);
        float sd = sqrtf(var);

        // median of 20 = average of order stats 9 and 10 (rank selection,
        // stable tie-break so duplicates are handled exactly)
        float med_lo = 0.f, med_hi = 0.f;
        #pragma unroll
        for (int i = 0; i < WLEN; ++i) {
            int rank = 0;
            #pragma unroll
            for (int j = 0; j < WLEN; ++j)
                rank += (v[j] < v[i]) || (v[j] == v[i] && j < i);
            if (rank == 9)  med_lo = v[i];
            if (rank == 10) med_hi = v[i];
        }
        float median = 0.5f * (med_lo + med_hi);
        float ratio = v[WLEN - 1] / (v[0] + 0.01f) - 1.0f;

        size_t base = ((size_t)b * NWIN + nw) * DIN;
        feat[base +  90 + f] = sd;
        feat[base + 100 + f] = mean / (sd + 0.01f);
        feat[base + 110 + f] = ratio;
        feat[base + 120 + f] = wsum;
        feat[base + 130 + f] = mean;
        feat[base + 140 + f] = minv;
        feat[base + 150 + f] = var;
        feat[base + 160 + f] = sum;
        feat[base + 170 + f] = median;
        float s3 = sd * sd * sd;
        feat[base + 180 + f] = m3 / (s3 + 0.01f);
        feat[base + 190 + f] = m4 / (s3 * sd + 0.01f) - 3.0f;
        feat[base + 200 + f] = sum;
        mean_s[f * NWIN + nw] = mean;
        std_s[f * NWIN + nw] = sd;
    }
    __syncthreads();

    for (int task = tid; task < NPAIR * NWIN; task += 256) {
        int p = task / NWIN, nw = task % NWIN;
        int fa = comb_a[p], fb = comb_b[p];
        float ma = mean_s[fa * NWIN + nw], mb = mean_s[fb * NWIN + nw];
        float sa = std_s[fa * NWIN + nw], sb = std_s[fb * NWIN + nw];
        const float* pa = &xs[fa * TLEN + nw * WLEN];
        const float* pb = &xs[fb * TLEN + nw * WLEN];
        float s = 0.f;
        #pragma unroll
        for (int t = 0; t < WLEN; ++t) s += (pa[t] - ma) * (pb[t] - mb);
        float cov = s * (1.0f / (WLEN - 1));
        float corr = cov / (sa * sb + 0.01f);
        size_t base = ((size_t)b * NWIN + nw) * DIN;
        feat[base + p] = corr;
        feat[base + NPAIR + p] = cov;
    }
}

// Per-group sum / sumsq over the raw stats. Tasks = (row, group).
__global__ __launch_bounds__(256)
void bn_reduce_kernel(const float* __restrict__ feat, double* __restrict__ accum) {
    __shared__ float sgs[NG], sgq[NG];
    int tid = threadIdx.x;
    if (tid < NG) { sgs[tid] = 0.f; sgq[tid] = 0.f; }
    __syncthreads();
    const long ROWS = (long)BATCH * NWIN;
    const long TASKS = ROWS * NG;
    for (long task = (long)blockIdx.x * blockDim.x + tid; task < TASKS;
         task += (long)gridDim.x * blockDim.x) {
        int g = (int)(task % NG);
        long row = task / NG;
        int ch0 = (g == 0) ? 0 : (g == 1) ? 45 : 90 + 10 * (g - 2);
        int n = (g < 2) ? 45 : 10;
        const float* p = feat + row * DIN + ch0;
        float s = 0.f, q = 0.f;
        for (int i = 0; i < n; ++i) { float v = p[i]; s += v; q += v * v; }
        atomicAdd(&sgs[g], s);
        atomicAdd(&sgq[g], q);
    }
    __syncthreads();
    if (tid < NG) {
        atomicAdd(&accum[tid],      (double)sgs[tid]);
        atomicAdd(&accum[NG + tid], (double)sgq[tid]);
    }
}

// Fused 2-layer GRU. One block = 8 batch rows, 192 threads = one per gate.
__global__ __launch_bounds__(192)
void gru_kernel(const float* __restrict__ feat,
                const double* __restrict__ accum,
                const float* __restrict__ WT,
                const float* __restrict__ bih0, const float* __restrict__ bhh0,
                const float* __restrict__ bih1, const float* __restrict__ bhh1,
                const float* __restrict__ conv_w, const float* __restrict__ conv_b,
                const float* __restrict__ bn_gamma, const float* __restrict__ bn_beta,
                float* __restrict__ out) {
    __shared__ float xs[BB][DIN];
    __shared__ float h0[BB][HID];
    __shared__ float h1[BB][HID];
    __shared__ float gi[BB][GATES];
    __shared__ float gh[BB][GATES];
    __shared__ float sc14[NG], sh14[NG];

    int tid = threadIdx.x;
    int b0 = blockIdx.x * BB;

    if (tid < NG) {
        double N = (tid < 2) ? (double)BATCH * NPAIR * NWIN : (double)BATCH * NF * NWIN;
        double m = accum[tid] / N;
        double v = accum[NG + tid] / N - m * m;
        float cw = conv_w[0], cb = conv_b[0];
        float A = bn_gamma[tid] * rsqrtf(cw * cw * (float)v + 1e-5f);
        float sc = A * cw;
        sc14[tid] = sc;
        sh14[tid] = bn_beta[tid] - sc * (float)m;   // A*cb cancels: beta - A*(m_y - cb) ... = beta - sc*m_s
    }
    for (int i = tid; i < BB * HID; i += GATES) {
        (&h0[0][0])[i] = 0.f;
        (&h1[0][0])[i] = 0.f;
    }
    __syncthreads();

    const float* WihT0 = WT;
    const float* WhhT0 = WT + DIN * GATES;
    const float* WihT1 = WhhT0 + HID * GATES;
    const float* WhhT1 = WihT1 + HID * GATES;

    for (int t = 0; t < NWIN; ++t) {
        // load + BN-affine the input tile
        for (int i = tid; i < BB * DIN; i += GATES) {
            int bb = i / DIN, ch = i % DIN;
            int g = (ch < 90) ? (ch / 45) : 2 + (ch - 90) / 10;
            float raw = feat[((size_t)(b0 + bb) * NWIN + t) * DIN + ch];
            xs[bb][ch] = sc14[g] * raw + sh14[g];
        }
        __syncthreads();

        // ----- layer 0 gates -----
        {
            int g = tid;
            float ai[BB], ah[BB];
            #pragma unroll
            for (int bb = 0; bb < BB; ++bb) { ai[bb] = bih0[g]; ah[bb] = bhh0[g]; }
            for (int k = 0; k < DIN; ++k) {
                float w = WihT0[k * GATES + g];
                #pragma unroll
                for (int bb = 0; bb < BB; ++bb) ai[bb] += w * xs[bb][k];
            }
            for (int k = 0; k < HID; ++k) {
                float w = WhhT0[k * GATES + g];
                #pragma unroll
                for (int bb = 0; bb < BB; ++bb) ah[bb] += w * h0[bb][k];
            }
            #pragma unroll
            for (int bb = 0; bb < BB; ++bb) { gi[bb][g] = ai[bb]; gh[bb][g] = ah[bb]; }
        }
        __syncthreads();
        if (tid < HID) {
            int j = tid;
            #pragma unroll
            for (int bb = 0; bb < BB; ++bb) {
                float r = 1.f / (1.f + expf(-(gi[bb][j] + gh[bb][j])));
                float z = 1.f / (1.f + expf(-(gi[bb][HID + j] + gh[bb][HID + j])));
                float n = tanhf(gi[bb][2 * HID + j] + r * gh[bb][2 * HID + j]);
                h0[bb][j] = (1.f - z) * n + z * h0[bb][j];
            }
        }
        __syncthreads();

        // ----- layer 1 gates -----
        {
            int g = tid;
            float ai[BB], ah[BB];
            #pragma unroll
            for (int bb = 0; bb < BB; ++bb) { ai[bb] = bih1[g]; ah[bb] = bhh1[g]; }
            for (int k = 0; k < HID; ++k) {
                float w1 = WihT1[k * GATES + g];
                float w2 = WhhT1[k * GATES + g];
                #pragma unroll
                for (int bb = 0; bb < BB; ++bb) {
                    ai[bb] += w1 * h0[bb][k];
                    ah[bb] += w2 * h1[bb][k];
                }
            }
            #pragma unroll
            for (int bb = 0; bb < BB; ++bb) { gi[bb][g] = ai[bb]; gh[bb][g] = ah[bb]; }
        }
        __syncthreads();
        if (tid < HID) {
            int j = tid;
            #pragma unroll
            for (int bb = 0; bb < BB; ++bb) {
                float r = 1.f / (1.f + expf(-(gi[bb][j] + gh[bb][j])));
                float z = 1.f / (1.f + expf(-(gi[bb][HID + j] + gh[bb][HID + j])));
                float n = tanhf(gi[bb][2 * HID + j] + r * gh[bb][2 * HID + j]);
                h1[bb][j] = (1.f - z) * n + z * h1[bb][j];
            }
        }
        __syncthreads();
    }

    for (int i = tid; i < BB * HID; i += GATES) {
        int bb = i / HID, j = i % HID;
        out[(size_t)(b0 + bb) * HID + j] = h1[bb][j];
    }
}

extern "C" void kernel_launch(void* const* d_in, const int* in_sizes, int n_in,
                              void* d_out, int out_size, void* d_ws, size_t ws_size,
                              hipStream_t stream) {
    const float* data     = (const float*)d_in[0];
    const float* conv_w   = (const float*)d_in[1];
    const float* conv_b   = (const float*)d_in[2];
    const float* bn_gamma = (const float*)d_in[3];
    const float* bn_beta  = (const float*)d_in[4];
    const float* Wih0     = (const float*)d_in[5];
    const float* Whh0     = (const float*)d_in[6];
    const float* bih0     = (const float*)d_in[7];
    const float* bhh0     = (const float*)d_in[8];
    const float* Wih1     = (const float*)d_in[9];
    const float* Whh1     = (const float*)d_in[10];
    const float* bih1     = (const float*)d_in[11];
    const float* bhh1     = (const float*)d_in[12];
    const int*  comb_a    = (const int*)d_in[13];
    const int*  comb_b    = (const int*)d_in[14];
    float* out = (float*)d_out;

    char* ws = (char*)d_ws;
    float* feat = (float*)ws;
    size_t feat_bytes = (size_t)BATCH * NWIN * DIN * sizeof(float);
    double* accum = (double*)(ws + feat_bytes);
    float* WT = (float*)(ws + feat_bytes + 256);

    hipMemsetAsync(accum, 0, 2 * NG * sizeof(double), stream);
    prep_kernel<<<64, 256, 0, stream>>>(Wih0, Whh0, Wih1, Whh1, WT);
    stats_kernel<<<BATCH, 256, 0, stream>>>(data, comb_a, comb_b, feat);
    bn_reduce_kernel<<<512, 256, 0, stream>>>(feat, accum);
    gru_kernel<<<BATCH / BB, 192, 0, stream>>>(feat, accum, WT,
                                               bih0, bhh0, bih1, bhh1,
                                               conv_w, conv_b, bn_gamma, bn_beta, out);
}

// Round 2
// 614.441 us; speedup vs baseline: 1.6861x; 1.6861x over previous
//
#include <hip/hip_runtime.h>
#include <math.h>

#define BATCH 4096
#define NF 10
#define TLEN 480
#define NWIN 24
#define WLEN 20
#define HID 64
#define NPAIR 45
#define DIN 210
#define DINP 212            // padded to float4 multiple
#define NQ0 (DINP/4)        // 53 k-quads for ih0
#define NQH (HID/4)         // 16 k-quads for hidden
#define NG 14
#define GATES 192
#define BB 8                // batch rows per recurrence block
#define MROWS 16            // rows per phaseA block

__device__ __forceinline__ int grp(int k) { return (k < 90) ? (k / 45) : 2 + (k - 90) / 10; }

// ---------------------------------------------------------------------------
// stats: one block per batch element (unchanged from R1, passing)
// ---------------------------------------------------------------------------
__global__ __launch_bounds__(256)
void stats_kernel(const float* __restrict__ data,
                  const int* __restrict__ comb_a,
                  const int* __restrict__ comb_b,
                  float* __restrict__ feat) {
    __shared__ float xs[NF * TLEN];
    __shared__ float mean_s[NF * NWIN];
    __shared__ float std_s[NF * NWIN];
    int b = blockIdx.x;
    int tid = threadIdx.x;
    const float* src = data + (size_t)b * (NF * TLEN);
    for (int i = tid; i < NF * TLEN; i += 256) xs[i] = src[i];
    __syncthreads();

    if (tid < NF * NWIN) {
        int f = tid / NWIN, nw = tid % NWIN;
        float v[WLEN];
        const float* p = &xs[f * TLEN + nw * WLEN];
        #pragma unroll
        for (int t = 0; t < WLEN; ++t) v[t] = p[t];

        float sum = 0.f, minv = v[0], wsum = 0.f;
        #pragma unroll
        for (int t = 0; t < WLEN; ++t) {
            sum += v[t];
            minv = fminf(minv, v[t]);
            wsum += v[t] * ((float)(t + 1) * (1.0f / 210.0f));
        }
        float mean = sum * (1.0f / WLEN);
        float var = 0.f, m3 = 0.f, m4 = 0.f;
        #pragma unroll
        for (int t = 0; t < WLEN; ++t) {
            float c = v[t] - mean;
            float c2 = c * c;
            var += c2; m3 += c2 * c; m4 += c2 * c2;
        }
        var *= (1.0f / WLEN); m3 *= (1.0f / WLEN); m4 *= (1.0f / WLEN);
        float sd = sqrtf(var);

        float med_lo = 0.f, med_hi = 0.f;
        #pragma unroll
        for (int i = 0; i < WLEN; ++i) {
            int rank = 0;
            #pragma unroll
            for (int j = 0; j < WLEN; ++j)
                rank += (v[j] < v[i]) || (v[j] == v[i] && j < i);
            if (rank == 9)  med_lo = v[i];
            if (rank == 10) med_hi = v[i];
        }
        float median = 0.5f * (med_lo + med_hi);
        float ratio = v[WLEN - 1] / (v[0] + 0.01f) - 1.0f;

        size_t base = ((size_t)b * NWIN + nw) * DIN;
        feat[base +  90 + f] = sd;
        feat[base + 100 + f] = mean / (sd + 0.01f);
        feat[base + 110 + f] = ratio;
        feat[base + 120 + f] = wsum;
        feat[base + 130 + f] = mean;
        feat[base + 140 + f] = minv;
        feat[base + 150 + f] = var;
        feat[base + 160 + f] = sum;
        feat[base + 170 + f] = median;
        float s3 = sd * sd * sd;
        feat[base + 180 + f] = m3 / (s3 + 0.01f);
        feat[base + 190 + f] = m4 / (s3 * sd + 0.01f) - 3.0f;
        feat[base + 200 + f] = sum;
        mean_s[f * NWIN + nw] = mean;
        std_s[f * NWIN + nw] = sd;
    }
    __syncthreads();

    for (int task = tid; task < NPAIR * NWIN; task += 256) {
        int p = task / NWIN, nw = task % NWIN;
        int fa = comb_a[p], fb = comb_b[p];
        float ma = mean_s[fa * NWIN + nw], mb = mean_s[fb * NWIN + nw];
        float sa = std_s[fa * NWIN + nw], sb = std_s[fb * NWIN + nw];
        const float* pa = &xs[fa * TLEN + nw * WLEN];
        const float* pb = &xs[fb * TLEN + nw * WLEN];
        float s = 0.f;
        #pragma unroll
        for (int t = 0; t < WLEN; ++t) s += (pa[t] - ma) * (pb[t] - mb);
        float cov = s * (1.0f / (WLEN - 1));
        float corr = cov / (sa * sb + 0.01f);
        size_t base = ((size_t)b * NWIN + nw) * DIN;
        feat[base + p] = corr;
        feat[base + NPAIR + p] = cov;
    }
}

// ---------------------------------------------------------------------------
// BN group reduction (unchanged)
// ---------------------------------------------------------------------------
__global__ __launch_bounds__(256)
void bn_reduce_kernel(const float* __restrict__ feat, double* __restrict__ accum) {
    __shared__ float sgs[NG], sgq[NG];
    int tid = threadIdx.x;
    if (tid < NG) { sgs[tid] = 0.f; sgq[tid] = 0.f; }
    __syncthreads();
    const long ROWS = (long)BATCH * NWIN;
    const long TASKS = ROWS * NG;
    for (long task = (long)blockIdx.x * blockDim.x + tid; task < TASKS;
         task += (long)gridDim.x * blockDim.x) {
        int g = (int)(task % NG);
        long row = task / NG;
        int ch0 = (g == 0) ? 0 : (g == 1) ? 45 : 90 + 10 * (g - 2);
        int n = (g < 2) ? 45 : 10;
        const float* p = feat + row * DIN + ch0;
        float s = 0.f, q = 0.f;
        for (int i = 0; i < n; ++i) { float v = p[i]; s += v; q += v * v; }
        atomicAdd(&sgs[g], s);
        atomicAdd(&sgq[g], q);
    }
    __syncthreads();
    if (tid < NG) {
        atomicAdd(&accum[tid],      (double)sgs[tid]);
        atomicAdd(&accum[NG + tid], (double)sgq[tid]);
    }
}

// ---------------------------------------------------------------------------
// prep: fold BN affine into ih0 weights + transpose/pack all weights as
// k-quads: Wq[k/4][192][4] so the GEMMs use dwordx4 weight loads.
// ---------------------------------------------------------------------------
__global__ __launch_bounds__(256)
void prep_kernel(const float* __restrict__ Wih0, const float* __restrict__ Whh0,
                 const float* __restrict__ Wih1, const float* __restrict__ Whh1,
                 const float* __restrict__ bih0, const double* __restrict__ accum,
                 const float* __restrict__ conv_w, const float* __restrict__ bn_gamma,
                 const float* __restrict__ bn_beta,
                 float* __restrict__ Wq0, float* __restrict__ bf0,
                 float* __restrict__ Wqh0, float* __restrict__ Wqi1,
                 float* __restrict__ Wqh1) {
    __shared__ float scs[NG], shs[NG];
    int tid = threadIdx.x;
    if (tid < NG) {
        double N = (tid < 2) ? (double)BATCH * NPAIR * NWIN : (double)BATCH * NF * NWIN;
        double m = accum[tid] / N;
        double v = accum[NG + tid] / N - m * m;
        float cw = conv_w[0];
        float A = bn_gamma[tid] * rsqrtf(cw * cw * (float)v + 1e-5f);
        float sc = A * cw;
        scs[tid] = sc;
        shs[tid] = bn_beta[tid] - sc * (float)m;
    }
    __syncthreads();

    const int NA = NQ0 * GATES * 4;   // 40704
    const int NB = NQH * GATES * 4;   // 12288
    int stride = gridDim.x * 256;
    for (int idx = blockIdx.x * 256 + tid; idx < NA + 3 * NB; idx += stride) {
        if (idx < NA) {
            int j = idx & 3, rest = idx >> 2;
            int g = rest % GATES, q = rest / GATES, k = q * 4 + j;
            Wq0[idx] = (k < DIN) ? Wih0[g * DIN + k] * scs[grp(k)] : 0.f;
        } else {
            int e = idx - NA;
            int which = e / NB; e %= NB;
            int j = e & 3, rest = e >> 2;
            int g = rest % GATES, q = rest / GATES, k = q * 4 + j;
            float v = 0.f;
            if (which == 0) v = Whh0[g * HID + k];
            else if (which == 1) v = Wih1[g * HID + k];
            else v = Whh1[g * HID + k];
            if (which == 0) Wqh0[e] = v; else if (which == 1) Wqi1[e] = v; else Wqh1[e] = v;
        }
    }
    if (blockIdx.x == 0 && tid < GATES) {
        float s = bih0[tid];
        for (int k = 0; k < DIN; ++k) s += Wih0[tid * DIN + k] * shs[grp(k)];
        bf0[tid] = s;
    }
}

// ---------------------------------------------------------------------------
// phase A: gi0[98304][192] = feat @ Wf0^T + bf0  (fp32, fully parallel)
// ---------------------------------------------------------------------------
__global__ __launch_bounds__(768, 6)
void phaseA_kernel(const float* __restrict__ feat, const float* __restrict__ Wq0,
                   const float* __restrict__ bf0, float* __restrict__ gi0) {
    __shared__ __align__(16) float xs[MROWS][DINP];
    int tid = threadIdx.x;
    size_t row0 = (size_t)blockIdx.x * MROWS;
    for (int i = tid; i < MROWS * DINP; i += 768) {
        int r = i / DINP, c = i % DINP;
        xs[r][c] = (c < DIN) ? feat[(row0 + r) * DIN + c] : 0.f;
    }
    __syncthreads();
    int g = tid % GATES, rq = tid / GATES;   // rq in 0..3 -> rows rq*4..rq*4+3
    const float4* w0 = (const float4*)Wq0;
    const float4* x0 = (const float4*)&xs[rq * 4 + 0][0];
    const float4* x1 = (const float4*)&xs[rq * 4 + 1][0];
    const float4* x2 = (const float4*)&xs[rq * 4 + 2][0];
    const float4* x3 = (const float4*)&xs[rq * 4 + 3][0];
    float a0 = 0.f, a1 = 0.f, a2 = 0.f, a3 = 0.f;
    #pragma unroll 2
    for (int q = 0; q < NQ0; ++q) {
        float4 w = w0[q * GATES + g];
        float4 pa = x0[q], pb = x1[q], pc = x2[q], pd = x3[q];
        a0 += w.x * pa.x + w.y * pa.y + w.z * pa.z + w.w * pa.w;
        a1 += w.x * pb.x + w.y * pb.y + w.z * pb.z + w.w * pb.w;
        a2 += w.x * pc.x + w.y * pc.y + w.z * pc.z + w.w * pc.w;
        a3 += w.x * pd.x + w.y * pd.y + w.z * pd.z + w.w * pd.w;
    }
    float bf = bf0[g];
    gi0[(row0 + rq * 4 + 0) * GATES + g] = a0 + bf;
    gi0[(row0 + rq * 4 + 1) * GATES + g] = a1 + bf;
    gi0[(row0 + rq * 4 + 2) * GATES + g] = a2 + bf;
    gi0[(row0 + rq * 4 + 3) * GATES + g] = a3 + bf;
}

// ---------------------------------------------------------------------------
// recurrence: 512 blocks x 768 threads (24 waves/CU). thread=(gate,row-quad),
// 2 rows/thread. HOISTED: gi0 precomputed; else ih0 inline.
// ---------------------------------------------------------------------------
template<bool HOISTED>
__global__ __launch_bounds__(768, 6)
void gru_rec_kernel(const float* __restrict__ feat, const float* __restrict__ gi0,
                    const float* __restrict__ Wq0, const float* __restrict__ bf0,
                    const float* __restrict__ Wqh0, const float* __restrict__ Wqi1,
                    const float* __restrict__ Wqh1,
                    const float* __restrict__ bhh0, const float* __restrict__ bih1,
                    const float* __restrict__ bhh1, float* __restrict__ out) {
    __shared__ float sgi[BB][GATES];
    __shared__ float sgh[BB][GATES];
    __shared__ __align__(16) float h0s[BB][HID];
    __shared__ __align__(16) float h1s[BB][HID];
    __shared__ __align__(16) float xs[BB][DINP];   // used only when !HOISTED

    int tid = threadIdx.x;
    int g = tid % GATES, rq = tid / GATES;
    int r0 = rq * 2, r1 = r0 + 1;
    int b0 = blockIdx.x * BB;

    float bhh0g = bhh0[g], bih1g = bih1[g], bhh1g = bhh1[g];
    float bf0g = HOISTED ? 0.f : bf0[g];

    if (tid < BB * HID) { ((float*)h0s)[tid] = 0.f; ((float*)h1s)[tid] = 0.f; }
    __syncthreads();

    const float4* wh0 = (const float4*)Wqh0;
    const float4* wi1 = (const float4*)Wqi1;
    const float4* wh1 = (const float4*)Wqh1;
    const float4* w0q = (const float4*)Wq0;

    for (int t = 0; t < NWIN; ++t) {
        float pre0 = 0.f, pre1 = 0.f;
        if (HOISTED) {
            // issue gi0 loads early; ds_write after the hh0 compute (T14 style)
            int i0 = tid, i1 = tid + 768;
            pre0 = gi0[(((size_t)(b0 + i0 / GATES)) * NWIN + t) * GATES + (i0 % GATES)];
            pre1 = gi0[(((size_t)(b0 + i1 / GATES)) * NWIN + t) * GATES + (i1 % GATES)];
        } else {
            for (int i = tid; i < BB * DINP; i += 768) {
                int r = i / DINP, c = i % DINP;
                xs[r][c] = (c < DIN) ? feat[(((size_t)(b0 + r)) * NWIN + t) * DIN + c] : 0.f;
            }
            __syncthreads();
        }

        // ----- layer-0 hidden gates: ah = h0 @ Whh0^T -----
        float ah0 = bhh0g, ah1 = bhh0g;
        {
            const float4* ha = (const float4*)&h0s[r0][0];
            const float4* hb = (const float4*)&h0s[r1][0];
            #pragma unroll 4
            for (int q = 0; q < NQH; ++q) {
                float4 w = wh0[q * GATES + g];
                float4 a = ha[q], b = hb[q];
                ah0 += w.x * a.x + w.y * a.y + w.z * a.z + w.w * a.w;
                ah1 += w.x * b.x + w.y * b.y + w.z * b.z + w.w * b.w;
            }
        }
        if (HOISTED) {
            ((float*)sgi)[tid] = pre0;
            ((float*)sgi)[tid + 768] = pre1;
        } else {
            float ai0 = bf0g, ai1 = bf0g;
            const float4* xa = (const float4*)&xs[r0][0];
            const float4* xb = (const float4*)&xs[r1][0];
            #pragma unroll 4
            for (int q = 0; q < NQ0; ++q) {
                float4 w = w0q[q * GATES + g];
                float4 a = xa[q], b = xb[q];
                ai0 += w.x * a.x + w.y * a.y + w.z * a.z + w.w * a.w;
                ai1 += w.x * b.x + w.y * b.y + w.z * b.z + w.w * b.w;
            }
            sgi[r0][g] = ai0; sgi[r1][g] = ai1;
        }
        sgh[r0][g] = ah0; sgh[r1][g] = ah1;
        __syncthreads();

        // ----- pointwise layer 0 -----
        if (tid < BB * HID) {
            int r = tid >> 6, j = tid & 63;
            float ir = sgi[r][j], iz = sgi[r][j + 64], in_ = sgi[r][j + 128];
            float hr = sgh[r][j], hz = sgh[r][j + 64], hn = sgh[r][j + 128];
            float rr = 1.f / (1.f + expf(-(ir + hr)));
            float zz = 1.f / (1.f + expf(-(iz + hz)));
            float nn = tanhf(in_ + rr * hn);
            h0s[r][j] = (1.f - zz) * nn + zz * h0s[r][j];
        }
        __syncthreads();

        // ----- layer-1 gates: ai = h0 @ Wih1^T, ah = h1 @ Whh1^T -----
        {
            float ai0 = bih1g, ai1 = bih1g, ch0 = bhh1g, ch1 = bhh1g;
            const float4* pa = (const float4*)&h0s[r0][0];
            const float4* pb = (const float4*)&h0s[r1][0];
            const float4* pc = (const float4*)&h1s[r0][0];
            const float4* pd = (const float4*)&h1s[r1][0];
            #pragma unroll 4
            for (int q = 0; q < NQH; ++q) {
                float4 wi = wi1[q * GATES + g];
                float4 wh = wh1[q * GATES + g];
                float4 a = pa[q], b = pb[q], c = pc[q], d = pd[q];
                ai0 += wi.x * a.x + wi.y * a.y + wi.z * a.z + wi.w * a.w;
                ai1 += wi.x * b.x + wi.y * b.y + wi.z * b.z + wi.w * b.w;
                ch0 += wh.x * c.x + wh.y * c.y + wh.z * c.z + wh.w * c.w;
                ch1 += wh.x * d.x + wh.y * d.y + wh.z * d.z + wh.w * d.w;
            }
            sgi[r0][g] = ai0; sgi[r1][g] = ai1;
            sgh[r0][g] = ch0; sgh[r1][g] = ch1;
        }
        __syncthreads();

        // ----- pointwise layer 1 -----
        if (tid < BB * HID) {
            int r = tid >> 6, j = tid & 63;
            float ir = sgi[r][j], iz = sgi[r][j + 64], in_ = sgi[r][j + 128];
            float hr = sgh[r][j], hz = sgh[r][j + 64], hn = sgh[r][j + 128];
            float rr = 1.f / (1.f + expf(-(ir + hr)));
            float zz = 1.f / (1.f + expf(-(iz + hz)));
            float nn = tanhf(in_ + rr * hn);
            h1s[r][j] = (1.f - zz) * nn + zz * h1s[r][j];
        }
        __syncthreads();
    }

    if (tid < BB * HID) {
        int r = tid >> 6, j = tid & 63;
        out[((size_t)(b0 + r)) * HID + j] = h1s[r][j];
    }
}

// ---------------------------------------------------------------------------
extern "C" void kernel_launch(void* const* d_in, const int* in_sizes, int n_in,
                              void* d_out, int out_size, void* d_ws, size_t ws_size,
                              hipStream_t stream) {
    const float* data     = (const float*)d_in[0];
    const float* conv_w   = (const float*)d_in[1];
    const float* bn_gamma = (const float*)d_in[3];
    const float* bn_beta  = (const float*)d_in[4];
    const float* Wih0     = (const float*)d_in[5];
    const float* Whh0     = (const float*)d_in[6];
    const float* bih0     = (const float*)d_in[7];
    const float* bhh0     = (const float*)d_in[8];
    const float* Wih1     = (const float*)d_in[9];
    const float* Whh1     = (const float*)d_in[10];
    const float* bih1     = (const float*)d_in[11];
    const float* bhh1     = (const float*)d_in[12];
    const int*  comb_a    = (const int*)d_in[13];
    const int*  comb_b    = (const int*)d_in[14];
    float* out = (float*)d_out;

    char* ws = (char*)d_ws;
    const size_t feat_bytes = (size_t)BATCH * NWIN * DIN * sizeof(float);      // 82,575,360
    const size_t wbase = feat_bytes;
    float* feat = (float*)ws;
    float* Wq0  = (float*)(ws + wbase);
    float* bf0  = (float*)(ws + wbase + 162816);
    float* Wqh0 = (float*)(ws + wbase + 163584);
    float* Wqi1 = (float*)(ws + wbase + 212736);
    float* Wqh1 = (float*)(ws + wbase + 261888);
    double* accum = (double*)(ws + wbase + 311296);
    float* gi0  = (float*)(ws + wbase + 311296 + 256);
    const size_t gi0_bytes = (size_t)BATCH * NWIN * GATES * sizeof(float);     // 75,497,472
    const size_t need_hoisted = wbase + 311296 + 256 + gi0_bytes;
    bool hoisted = (ws_size >= need_hoisted);

    hipMemsetAsync(accum, 0, 2 * NG * sizeof(double), stream);
    stats_kernel<<<BATCH, 256, 0, stream>>>(data, comb_a, comb_b, feat);
    bn_reduce_kernel<<<512, 256, 0, stream>>>(feat, accum);
    prep_kernel<<<64, 256, 0, stream>>>(Wih0, Whh0, Wih1, Whh1, bih0, accum,
                                        conv_w, bn_gamma, bn_beta,
                                        Wq0, bf0, Wqh0, Wqi1, Wqh1);
    if (hoisted) {
        phaseA_kernel<<<(BATCH * NWIN) / MROWS, 768, 0, stream>>>(feat, Wq0, bf0, gi0);
        gru_rec_kernel<true><<<BATCH / BB, 768, 0, stream>>>(feat, gi0, Wq0, bf0,
                                                             Wqh0, Wqi1, Wqh1,
                                                             bhh0, bih1, bhh1, out);
    } else {
        gru_rec_kernel<false><<<BATCH / BB, 768, 0, stream>>>(feat, gi0, Wq0, bf0,
                                                              Wqh0, Wqi1, Wqh1,
                                                              bhh0, bih1, bhh1, out);
    }
}

// Round 3
// 287.377 us; speedup vs baseline: 3.6051x; 2.1381x over previous
//
#include <hip/hip_runtime.h>
#include <math.h>

#define BATCH 4096
#define NF 10
#define TLEN 480
#define NWIN 24
#define WLEN 20
#define HID 64
#define NPAIR 45
#define DIN 210
#define FROW 212            // global feat row (floats), 848B = 53*16 aligned
#define LROW 228            // LDS feat row (floats), bank-spread + 16B aligned
#define NG 14
#define GATES 192

typedef __attribute__((ext_vector_type(8))) short bf16x8;
typedef __attribute__((ext_vector_type(4))) float f32x4;

__device__ __forceinline__ int grp(int k) { return (k < 90) ? (k / 45) : 2 + (k - 90) / 10; }

__device__ __forceinline__ void split2(float x, short& hi, short& lo) {
    unsigned u = __float_as_uint(x);
    hi = (short)(u >> 16);
    float hf = __uint_as_float(u & 0xffff0000u);
    lo = (short)(__float_as_uint(x - hf) >> 16);
}

// ---------------------------------------------------------------------------
// stats + fused BN partial sums, coalesced feat writes.  feat: [b*24+nw][212]
// ---------------------------------------------------------------------------
__global__ __launch_bounds__(256)
void stats_kernel(const float* __restrict__ data,
                  const int* __restrict__ comb_a,
                  const int* __restrict__ comb_b,
                  float* __restrict__ feat,
                  float* __restrict__ accum) {
    __shared__ __align__(16) float xs[NF * TLEN];       // 19.2 KB
    __shared__ __align__(16) float tile[NWIN][FROW];    // 20.35 KB
    __shared__ float mean_s[NF * NWIN];
    __shared__ float std_s[NF * NWIN];
    __shared__ float sgs[NG], sgq[NG];
    int b = blockIdx.x;
    int tid = threadIdx.x;
    const float* src = data + (size_t)b * (NF * TLEN);
    #pragma unroll
    for (int i = 0; i < 5; ++i) {
        int q = tid + i * 256;
        if (q < 1200) *(float4*)&xs[q * 4] = *(const float4*)&src[q * 4];
    }
    if (tid < NG) { sgs[tid] = 0.f; sgq[tid] = 0.f; }
    if (tid < 48) tile[tid / 2][210 + (tid & 1)] = 0.f;   // zero pad cols
    __syncthreads();

    if (tid < NF * NWIN) {
        int f = tid / NWIN, nw = tid % NWIN;
        float v[WLEN];
        const float* p = &xs[f * TLEN + nw * WLEN];
        #pragma unroll
        for (int t = 0; t < WLEN; ++t) v[t] = p[t];

        float sum = 0.f, minv = v[0], wsum = 0.f;
        #pragma unroll
        for (int t = 0; t < WLEN; ++t) {
            sum += v[t];
            minv = fminf(minv, v[t]);
            wsum += v[t] * ((float)(t + 1) * (1.0f / 210.0f));
        }
        float mean = sum * (1.0f / WLEN);
        float var = 0.f, m3 = 0.f, m4 = 0.f;
        #pragma unroll
        for (int t = 0; t < WLEN; ++t) {
            float c = v[t] - mean;
            float c2 = c * c;
            var += c2; m3 += c2 * c; m4 += c2 * c2;
        }
        var *= (1.0f / WLEN); m3 *= (1.0f / WLEN); m4 *= (1.0f / WLEN);
        float sd = sqrtf(var);

        float med_lo = 0.f, med_hi = 0.f;
        #pragma unroll
        for (int i = 0; i < WLEN; ++i) {
            int rank = 0;
            #pragma unroll
            for (int jj = 0; jj < WLEN; ++jj)
                rank += (v[jj] < v[i]) || (v[jj] == v[i] && jj < i);
            if (rank == 9)  med_lo = v[i];
            if (rank == 10) med_hi = v[i];
        }
        float median = 0.5f * (med_lo + med_hi);
        float ratio = v[WLEN - 1] / (v[0] + 0.01f) - 1.0f;

        tile[nw][ 90 + f] = sd;
        tile[nw][100 + f] = mean / (sd + 0.01f);
        tile[nw][110 + f] = ratio;
        tile[nw][120 + f] = wsum;
        tile[nw][130 + f] = mean;
        tile[nw][140 + f] = minv;
        tile[nw][150 + f] = var;
        tile[nw][160 + f] = sum;
        tile[nw][170 + f] = median;
        float s3 = sd * sd * sd;
        tile[nw][180 + f] = m3 / (s3 + 0.01f);
        tile[nw][190 + f] = m4 / (s3 * sd + 0.01f) - 3.0f;
        tile[nw][200 + f] = sum;
        mean_s[f * NWIN + nw] = mean;
        std_s[f * NWIN + nw] = sd;
    }
    __syncthreads();

    for (int task = tid; task < NPAIR * NWIN; task += 256) {
        int p = task / NWIN, nw = task % NWIN;
        int fa = comb_a[p], fb = comb_b[p];
        float ma = mean_s[fa * NWIN + nw], mb = mean_s[fb * NWIN + nw];
        float sa = std_s[fa * NWIN + nw], sb = std_s[fb * NWIN + nw];
        const float* pa = &xs[fa * TLEN + nw * WLEN];
        const float* pb = &xs[fb * TLEN + nw * WLEN];
        float s = 0.f;
        #pragma unroll
        for (int t = 0; t < WLEN; ++t) s += (pa[t] - ma) * (pb[t] - mb);
        float cov = s * (1.0f / (WLEN - 1));
        tile[nw][p] = cov / (sa * sb + 0.01f);
        tile[nw][NPAIR + p] = cov;
    }
    __syncthreads();

    // fused BN partial sums (raw stats; affine derived analytically later)
    for (int task = tid; task < NWIN * NG; task += 256) {
        int g = task % NG, row = task / NG;
        int ch0 = (g == 0) ? 0 : (g == 1) ? 45 : 90 + 10 * (g - 2);
        int n = (g < 2) ? 45 : 10;
        float s = 0.f, q = 0.f;
        for (int i = 0; i < n; ++i) { float v = tile[row][ch0 + i]; s += v; q += v * v; }
        atomicAdd(&sgs[g], s);
        atomicAdd(&sgq[g], q);
    }
    __syncthreads();
    if (tid < NG) {
        atomicAdd(&accum[tid], sgs[tid]);
        atomicAdd(&accum[NG + tid], sgq[tid]);
    }
    // coalesced write-out: 24*53 quads
    size_t gbase = (size_t)b * NWIN * FROW;
    for (int q = tid; q < NWIN * 53; q += 256) {
        int r = q / 53, c = (q % 53) * 4;
        *(float4*)&feat[gbase + r * FROW + c] = *(const float4*)&tile[r][c];
    }
}

// ---------------------------------------------------------------------------
// prep: BN-fold + split-bf16 pack into MFMA B-fragment layout.
//  hidden: WH[mat 3][prec 2][ks 2][ct 12][lane 64][8]
//  ih0   : W0[prec 2][ks 7][ct 12][lane 64][8]   (k>=210 zero, sc folded)
// ---------------------------------------------------------------------------
#define NHID_ELEMS (3*2*2*12*64*8)   // 73728
#define NIH0_ELEMS (2*7*12*64*8)     // 86016
__global__ __launch_bounds__(256)
void prep_kernel(const float* __restrict__ Wih0, const float* __restrict__ Whh0,
                 const float* __restrict__ Wih1, const float* __restrict__ Whh1,
                 const float* __restrict__ bih0, const float* __restrict__ accum,
                 const float* __restrict__ conv_w, const float* __restrict__ bn_gamma,
                 const float* __restrict__ bn_beta,
                 short* __restrict__ WH, short* __restrict__ W0p,
                 float* __restrict__ bf0) {
    __shared__ float scs[NG], shs[NG];
    int tid = threadIdx.x;
    if (tid < NG) {
        float N = (tid < 2) ? (float)BATCH * NPAIR * NWIN : (float)BATCH * NF * NWIN;
        float m = accum[tid] / N;
        float v = accum[NG + tid] / N - m * m;
        float cw = conv_w[0];
        float A = bn_gamma[tid] * rsqrtf(cw * cw * v + 1e-5f);
        float sc = A * cw;
        scs[tid] = sc;
        shs[tid] = bn_beta[tid] - sc * m;
    }
    __syncthreads();

    for (int i = blockIdx.x * 256 + tid; i < NHID_ELEMS + NIH0_ELEMS; i += gridDim.x * 256) {
        if (i < NHID_ELEMS) {
            int j = i & 7, lane = (i >> 3) & 63, rest = i >> 9;
            int ct = rest % 12; rest /= 12;
            int ks = rest & 1; rest >>= 1;
            int p = rest & 1; int m = rest >> 1;
            int g = ct * 16 + (lane & 15);
            int k = ks * 32 + ((lane >> 4) << 3) + j;
            const float* Wm = (m == 0) ? Whh0 : (m == 1) ? Wih1 : Whh1;
            float v = Wm[g * HID + k];
            short hi, lo; split2(v, hi, lo);
            WH[i] = p ? lo : hi;
        } else {
            int e = i - NHID_ELEMS;
            int j = e & 7, lane = (e >> 3) & 63, rest = e >> 9;
            int ct = rest % 12; rest /= 12;
            int ks = rest % 7; int p = rest / 7;
            int g = ct * 16 + (lane & 15);
            int k = ks * 32 + ((lane >> 4) << 3) + j;
            float v = (k < DIN) ? Wih0[g * DIN + k] * scs[grp(k)] : 0.f;
            short hi, lo; split2(v, hi, lo);
            W0p[e] = p ? lo : hi;
        }
    }
    if (blockIdx.x == 0 && tid < GATES) {
        float s = bih0[tid];
        for (int k = 0; k < DIN; ++k) s += Wih0[tid * DIN + k] * shs[grp(k)];
        bf0[tid] = s;
    }
}

// ---------------------------------------------------------------------------
// fused recurrence: 256 blocks x 256 thr; block = 16 batch rows; wave w owns
// gate cols j in [16w,16w+16).  ih0 inline (streamed B), hidden B in VGPRs.
// Split-bf16 3-pass MFMA; pointwise fully in-register.
// ---------------------------------------------------------------------------
#define MFMA(a,b,c) __builtin_amdgcn_mfma_f32_16x16x32_bf16((a),(b),(c),0,0,0)

__global__ __launch_bounds__(256, 1)
void rec_kernel(const float* __restrict__ feat,
                const short* __restrict__ WH, const short* __restrict__ W0p,
                const float* __restrict__ bf0,
                const float* __restrict__ bhh0, const float* __restrict__ bih1,
                const float* __restrict__ bhh1, float* __restrict__ out) {
    __shared__ __align__(16) float ft[2][16][LROW];     // 29.2 KB (pad zeroed)
    __shared__ __align__(16) short hp[4][16][72];       // h0hi,h0lo,h1hi,h1lo

    int tid = threadIdx.x;
    int w = tid >> 6, l = tid & 63;
    int lm = l & 15, kb = l >> 4;
    int b0 = blockIdx.x * 16;
    int j = w * 16 + lm;

    for (int i = tid; i < 2 * 16 * LROW; i += 256) ((float*)ft)[i] = 0.f;
    for (int i = tid; i < 4 * 16 * 72; i += 256) ((short*)hp)[i] = 0;

    // hidden weight fragments resident in VGPRs: [mat][prec][ks][role]
    bf16x8 WF[3][2][2][3];
    #pragma unroll
    for (int m = 0; m < 3; ++m)
        #pragma unroll
        for (int p = 0; p < 2; ++p)
            #pragma unroll
            for (int ks = 0; ks < 2; ++ks)
                #pragma unroll
                for (int role = 0; role < 3; ++role)
                    WF[m][p][ks][role] = *(const bf16x8*)(WH +
                        (((((m * 2 + p) * 2 + ks) * 12 + (role * 4 + w)) * 64 + l) << 3));

    float br0 = bf0[j] + bhh0[j];
    float bz0 = bf0[j + 64] + bhh0[j + 64];
    float bin0 = bf0[j + 128];
    float bhn0 = bhh0[j + 128];
    float br1 = bih1[j] + bhh1[j];
    float bz1 = bih1[j + 64] + bhh1[j + 64];
    float bin1 = bih1[j + 128];
    float bhn1 = bhh1[j + 128];

    float h0r[4] = {0.f, 0.f, 0.f, 0.f};
    float h1r[4] = {0.f, 0.f, 0.f, 0.f};

    // stage tile 0
    #pragma unroll
    for (int i = 0; i < 4; ++i) {
        int q = tid + i * 256;
        if (q < 848) {
            int r = q / 53, c = (q % 53) * 4;
            *(float4*)&ft[0][r][c] =
                *(const float4*)&feat[((size_t)(b0 + r) * NWIN + 0) * FROW + c];
        }
    }
    __syncthreads();

    #pragma unroll 1
    for (int t = 0; t < NWIN; ++t) {
        int buf = t & 1;
        // ---- A-fragments ----
        bf16x8 a0h[2], a0l[2], a1h[2], a1l[2];
        #pragma unroll
        for (int ks = 0; ks < 2; ++ks) {
            int off = ks * 32 + kb * 8;
            a0h[ks] = *(const bf16x8*)&hp[0][lm][off];
            a0l[ks] = *(const bf16x8*)&hp[1][lm][off];
            a1h[ks] = *(const bf16x8*)&hp[2][lm][off];
            a1l[ks] = *(const bf16x8*)&hp[3][lm][off];
        }
        bf16x8 fh[7], fl[7];
        #pragma unroll
        for (int ks = 0; ks < 7; ++ks) {
            const float* base = &ft[buf][lm][ks * 32 + kb * 8];
            float4 u0 = *(const float4*)base;
            float4 u1 = *(const float4*)(base + 4);
            short hi, lo;
            split2(u0.x, hi, lo); fh[ks][0] = hi; fl[ks][0] = lo;
            split2(u0.y, hi, lo); fh[ks][1] = hi; fl[ks][1] = lo;
            split2(u0.z, hi, lo); fh[ks][2] = hi; fl[ks][2] = lo;
            split2(u0.w, hi, lo); fh[ks][3] = hi; fl[ks][3] = lo;
            split2(u1.x, hi, lo); fh[ks][4] = hi; fl[ks][4] = lo;
            split2(u1.y, hi, lo); fh[ks][5] = hi; fl[ks][5] = lo;
            split2(u1.z, hi, lo); fh[ks][6] = hi; fl[ks][6] = lo;
            split2(u1.w, hi, lo); fh[ks][7] = hi; fl[ks][7] = lo;
        }
        __syncthreads();   // B1: frag reads done before h-plane writes

        // ---- prefetch next feat tile into regs ----
        float4 pf[4];
        if (t < NWIN - 1) {
            #pragma unroll
            for (int i = 0; i < 4; ++i) {
                int q = tid + i * 256;
                if (q < 848) {
                    int r = q / 53, c = (q % 53) * 4;
                    pf[i] = *(const float4*)&feat[((size_t)(b0 + r) * NWIN + t + 1) * FROW + c];
                }
            }
        }

        // ---- layer0 hh + layer1 hh MFMA (register B) ----
        f32x4 accr = {0,0,0,0}, accz = {0,0,0,0}, accgin = {0,0,0,0}, accghn = {0,0,0,0};
        f32x4 a1cr = {0,0,0,0}, a1cz = {0,0,0,0}, a1cgin = {0,0,0,0}, a1cghn = {0,0,0,0};
        #pragma unroll
        for (int ks = 0; ks < 2; ++ks) {
            accr = MFMA(a0h[ks], WF[0][0][ks][0], accr);
            accr = MFMA(a0h[ks], WF[0][1][ks][0], accr);
            accr = MFMA(a0l[ks], WF[0][0][ks][0], accr);
            accz = MFMA(a0h[ks], WF[0][0][ks][1], accz);
            accz = MFMA(a0h[ks], WF[0][1][ks][1], accz);
            accz = MFMA(a0l[ks], WF[0][0][ks][1], accz);
            accghn = MFMA(a0h[ks], WF[0][0][ks][2], accghn);
            accghn = MFMA(a0h[ks], WF[0][1][ks][2], accghn);
            accghn = MFMA(a0l[ks], WF[0][0][ks][2], accghn);
            a1cr = MFMA(a1h[ks], WF[2][0][ks][0], a1cr);
            a1cr = MFMA(a1h[ks], WF[2][1][ks][0], a1cr);
            a1cr = MFMA(a1l[ks], WF[2][0][ks][0], a1cr);
            a1cz = MFMA(a1h[ks], WF[2][0][ks][1], a1cz);
            a1cz = MFMA(a1h[ks], WF[2][1][ks][1], a1cz);
            a1cz = MFMA(a1l[ks], WF[2][0][ks][1], a1cz);
            a1cghn = MFMA(a1h[ks], WF[2][0][ks][2], a1cghn);
            a1cghn = MFMA(a1h[ks], WF[2][1][ks][2], a1cghn);
            a1cghn = MFMA(a1l[ks], WF[2][0][ks][2], a1cghn);
        }
        // ---- ih0 (streamed B, 3-pass) ----
        #pragma unroll
        for (int ks = 0; ks < 7; ++ks) {
            bf16x8 bh[3], bl[3];
            #pragma unroll
            for (int role = 0; role < 3; ++role) {
                bh[role] = *(const bf16x8*)(W0p + ((((0 * 7 + ks) * 12 + (role * 4 + w)) * 64 + l) << 3));
                bl[role] = *(const bf16x8*)(W0p + ((((1 * 7 + ks) * 12 + (role * 4 + w)) * 64 + l) << 3));
            }
            accr = MFMA(fh[ks], bh[0], accr);
            accr = MFMA(fh[ks], bl[0], accr);
            accr = MFMA(fl[ks], bh[0], accr);
            accz = MFMA(fh[ks], bh[1], accz);
            accz = MFMA(fh[ks], bl[1], accz);
            accz = MFMA(fl[ks], bh[1], accz);
            accgin = MFMA(fh[ks], bh[2], accgin);
            accgin = MFMA(fh[ks], bl[2], accgin);
            accgin = MFMA(fl[ks], bh[2], accgin);
        }

        // ---- pointwise layer 0 (register-only) ----
        #pragma unroll
        for (int reg = 0; reg < 4; ++reg) {
            int row = kb * 4 + reg;
            float gr = accr[reg] + br0;
            float gz = accz[reg] + bz0;
            float gin = accgin[reg] + bin0;
            float ghn = accghn[reg] + bhn0;
            float r = 1.f / (1.f + expf(-gr));
            float z = 1.f / (1.f + expf(-gz));
            float n = tanhf(gin + r * ghn);
            float h = (1.f - z) * n + z * h0r[reg];
            h0r[reg] = h;
            short hi, lo; split2(h, hi, lo);
            hp[0][row][j] = hi;
            hp[1][row][j] = lo;
        }
        __syncthreads();   // B2: h0 planes updated

        // ---- layer1 ih (A = new h0) ----
        bf16x8 n0h[2], n0l[2];
        #pragma unroll
        for (int ks = 0; ks < 2; ++ks) {
            int off = ks * 32 + kb * 8;
            n0h[ks] = *(const bf16x8*)&hp[0][lm][off];
            n0l[ks] = *(const bf16x8*)&hp[1][lm][off];
        }
        #pragma unroll
        for (int ks = 0; ks < 2; ++ks) {
            a1cr = MFMA(n0h[ks], WF[1][0][ks][0], a1cr);
            a1cr = MFMA(n0h[ks], WF[1][1][ks][0], a1cr);
            a1cr = MFMA(n0l[ks], WF[1][0][ks][0], a1cr);
            a1cz = MFMA(n0h[ks], WF[1][0][ks][1], a1cz);
            a1cz = MFMA(n0h[ks], WF[1][1][ks][1], a1cz);
            a1cz = MFMA(n0l[ks], WF[1][0][ks][1], a1cz);
            a1cgin = MFMA(n0h[ks], WF[1][0][ks][2], a1cgin);
            a1cgin = MFMA(n0h[ks], WF[1][1][ks][2], a1cgin);
            a1cgin = MFMA(n0l[ks], WF[1][0][ks][2], a1cgin);
        }
        // ---- pointwise layer 1 ----
        #pragma unroll
        for (int reg = 0; reg < 4; ++reg) {
            int row = kb * 4 + reg;
            float gr = a1cr[reg] + br1;
            float gz = a1cz[reg] + bz1;
            float gin = a1cgin[reg] + bin1;
            float ghn = a1cghn[reg] + bhn1;
            float r = 1.f / (1.f + expf(-gr));
            float z = 1.f / (1.f + expf(-gz));
            float n = tanhf(gin + r * ghn);
            float h = (1.f - z) * n + z * h1r[reg];
            h1r[reg] = h;
            short hi, lo; split2(h, hi, lo);
            hp[2][row][j] = hi;
            hp[3][row][j] = lo;
        }
        // ---- write prefetched tile ----
        if (t < NWIN - 1) {
            #pragma unroll
            for (int i = 0; i < 4; ++i) {
                int q = tid + i * 256;
                if (q < 848) {
                    int r = q / 53, c = (q % 53) * 4;
                    *(float4*)&ft[buf ^ 1][r][c] = pf[i];
                }
            }
        }
        __syncthreads();   // B3
    }

    #pragma unroll
    for (int reg = 0; reg < 4; ++reg)
        out[(size_t)(b0 + kb * 4 + reg) * HID + j] = h1r[reg];
}

// ---------------------------------------------------------------------------
extern "C" void kernel_launch(void* const* d_in, const int* in_sizes, int n_in,
                              void* d_out, int out_size, void* d_ws, size_t ws_size,
                              hipStream_t stream) {
    const float* data     = (const float*)d_in[0];
    const float* conv_w   = (const float*)d_in[1];
    const float* bn_gamma = (const float*)d_in[3];
    const float* bn_beta  = (const float*)d_in[4];
    const float* Wih0     = (const float*)d_in[5];
    const float* Whh0     = (const float*)d_in[6];
    const float* bih0     = (const float*)d_in[7];
    const float* bhh0     = (const float*)d_in[8];
    const float* Wih1     = (const float*)d_in[9];
    const float* Whh1     = (const float*)d_in[10];
    const float* bih1     = (const float*)d_in[11];
    const float* bhh1     = (const float*)d_in[12];
    const int*  comb_a    = (const int*)d_in[13];
    const int*  comb_b    = (const int*)d_in[14];
    float* out = (float*)d_out;

    char* ws = (char*)d_ws;
    const size_t feat_bytes = (size_t)BATCH * NWIN * FROW * sizeof(float);  // 83,361,792
    float* feat = (float*)ws;
    short* WH   = (short*)(ws + feat_bytes);                       // 147,456 B
    short* W0p  = (short*)(ws + feat_bytes + 147456);              // 172,032 B
    float* bf0  = (float*)(ws + feat_bytes + 147456 + 172032);     // 768 B
    float* accum = (float*)(ws + feat_bytes + 147456 + 172032 + 1024);  // 112 B

    hipMemsetAsync(accum, 0, 2 * NG * sizeof(float), stream);
    stats_kernel<<<BATCH, 256, 0, stream>>>(data, comb_a, comb_b, feat, accum);
    prep_kernel<<<640, 256, 0, stream>>>(Wih0, Whh0, Wih1, Whh1, bih0, accum,
                                         conv_w, bn_gamma, bn_beta, WH, W0p, bf0);
    rec_kernel<<<BATCH / 16, 256, 0, stream>>>(feat, WH, W0p, bf0,
                                               bhh0, bih1, bhh1, out);
}

// Round 4
// 235.315 us; speedup vs baseline: 4.4027x; 1.2212x over previous
//
#include <hip/hip_runtime.h>
#include <math.h>

#define NF 10
#define TLEN 480
#define NWIN 24
#define WLEN 20
#define HID 64
#define NPAIR 45
#define DIN 210
#define NG 14
#define GATES 192
#define NGRP 256            // 4096 / 16 rows per group
#define KP 224              // ih0 K padded to 7*32
#define FROW 212            // MODE0 fp32 feat row length

typedef __attribute__((ext_vector_type(8))) short bf16x8;
typedef __attribute__((ext_vector_type(4))) float f32x4;

#define MFMA(a,b,c) __builtin_amdgcn_mfma_f32_16x16x32_bf16((a),(b),(c),0,0,0)

__device__ __forceinline__ int grp_of(int k){ return (k < 90) ? (k / 45) : 2 + (k - 90) / 10; }

__device__ __forceinline__ void split2(float x, short& hi, short& lo){
    unsigned u = __float_as_uint(x);
    hi = (short)(u >> 16);
    float hf = __uint_as_float(u & 0xffff0000u);
    lo = (short)(__float_as_uint(x - hf) >> 16);
}
__device__ __forceinline__ short bf16rne(float x){
    unsigned u = __float_as_uint(x);
    u += 0x7fffu + ((u >> 16) & 1u);
    return (short)(u >> 16);
}
__device__ __forceinline__ float sigm(float x){
    return __builtin_amdgcn_rcpf(1.f + __builtin_amdgcn_exp2f(x * -1.4426950408889634f));
}
__device__ __forceinline__ float tanhfast(float x){
    return 1.f - 2.f * __builtin_amdgcn_rcpf(1.f + __builtin_amdgcn_exp2f(x * 2.8853900817779268f));
}

// ---------------------------------------------------------------------------
// stats: one block = 16 batch elements (one row-group), 512 threads.
// Emits (MODE1) bf16 hi/lo planes in MFMA A-fragment layout, or (MODE0)
// fp32 rows [tile][16][212]. Fused BN group sums.
// ---------------------------------------------------------------------------
template<int MODE>
__global__ __launch_bounds__(512)
void stats_kernel(const float* __restrict__ data, const int* __restrict__ comb_a,
                  const int* __restrict__ comb_b, short* __restrict__ planes,
                  float* __restrict__ feat32, float* __restrict__ accum)
{
    __shared__ float xs[2][NF * TLEN];          // 38.4 KB
    __shared__ float tile[2][NWIN][KP];         // 43 KB
    __shared__ float mean_s[2][240], std_s[2][240];
    __shared__ float sgs[NG], sgq[NG];
    int tid = threadIdx.x, blk = blockIdx.x;
    size_t b0 = (size_t)blk * 16;

    for (int i = tid; i < 2 * NWIN * (KP - DIN); i += 512){
        int e = i / (NWIN * (KP - DIN));
        int r = (i / (KP - DIN)) % NWIN;
        int c = i % (KP - DIN);
        tile[e][r][DIN + c] = 0.f;
    }
    if (tid < NG){ sgs[tid] = 0.f; sgq[tid] = 0.f; }
    __syncthreads();

    for (int pp = 0; pp < 8; ++pp){
        // stage two elements
        for (int q = tid; q < 2400; q += 512){
            int e = q / 1200, off = (q % 1200) * 4;
            *(float4*)&xs[e][off] = *(const float4*)&data[(b0 + pp * 2 + e) * (NF * TLEN) + off];
        }
        __syncthreads();

        if (tid < 480){
            int e = tid / 240, r = tid % 240, f = r / NWIN, nw = r % NWIN;
            const float* p = &xs[e][f * TLEN + nw * WLEN];
            float v[WLEN];
            #pragma unroll
            for (int i = 0; i < WLEN; ++i) v[i] = p[i];
            float sum = 0.f, minv = v[0], wsum = 0.f;
            #pragma unroll
            for (int i = 0; i < WLEN; ++i){
                sum += v[i];
                minv = fminf(minv, v[i]);
                wsum += v[i] * ((float)(i + 1) * (1.0f / 210.0f));
            }
            float mean = sum * (1.0f / WLEN);
            float var = 0.f, m3 = 0.f, m4 = 0.f;
            #pragma unroll
            for (int i = 0; i < WLEN; ++i){
                float c = v[i] - mean, c2 = c * c;
                var += c2; m3 += c2 * c; m4 += c2 * c2;
            }
            var *= 0.05f; m3 *= 0.05f; m4 *= 0.05f;
            float sd = sqrtf(var);
            // stable-rank median via 190 pairwise comparisons
            int rk[WLEN];
            #pragma unroll
            for (int i = 0; i < WLEN; ++i) rk[i] = 0;
            #pragma unroll
            for (int i = 0; i < WLEN; ++i)
                #pragma unroll
                for (int jj = i + 1; jj < WLEN; ++jj){
                    bool c = v[jj] < v[i];
                    rk[i] += c ? 1 : 0;
                    rk[jj] += c ? 0 : 1;
                }
            float med_lo = 0.f, med_hi = 0.f;
            #pragma unroll
            for (int i = 0; i < WLEN; ++i){
                if (rk[i] == 9)  med_lo = v[i];
                if (rk[i] == 10) med_hi = v[i];
            }
            float median = 0.5f * (med_lo + med_hi);
            float ratio = v[WLEN - 1] / (v[0] + 0.01f) - 1.0f;
            float s3 = sd * sd * sd;
            tile[e][nw][ 90 + f] = sd;
            tile[e][nw][100 + f] = mean / (sd + 0.01f);
            tile[e][nw][110 + f] = ratio;
            tile[e][nw][120 + f] = wsum;
            tile[e][nw][130 + f] = mean;
            tile[e][nw][140 + f] = minv;
            tile[e][nw][150 + f] = var;
            tile[e][nw][160 + f] = sum;
            tile[e][nw][170 + f] = median;
            tile[e][nw][180 + f] = m3 / (s3 + 0.01f);
            tile[e][nw][190 + f] = m4 / (s3 * sd + 0.01f) - 3.0f;
            tile[e][nw][200 + f] = sum;
            mean_s[e][f * NWIN + nw] = mean;
            std_s[e][f * NWIN + nw] = sd;
        }
        __syncthreads();

        for (int task = tid; task < 2160; task += 512){
            int e = task / 1080, q = task % 1080, pi = q / NWIN, nw = q % NWIN;
            int fa_ = comb_a[pi], fb_ = comb_b[pi];
            float ma = mean_s[e][fa_ * NWIN + nw], mb = mean_s[e][fb_ * NWIN + nw];
            float sa = std_s[e][fa_ * NWIN + nw], sb = std_s[e][fb_ * NWIN + nw];
            const float* pa = &xs[e][fa_ * TLEN + nw * WLEN];
            const float* pb = &xs[e][fb_ * TLEN + nw * WLEN];
            float s = 0.f;
            #pragma unroll
            for (int i = 0; i < WLEN; ++i) s += (pa[i] - ma) * (pb[i] - mb);
            float cov = s * (1.0f / (WLEN - 1));
            tile[e][nw][pi] = cov / (sa * sb + 0.01f);
            tile[e][nw][NPAIR + pi] = cov;
        }
        __syncthreads();

        // BN group sums + pack (both read-only on tile)
        for (int task = tid; task < 672; task += 512){
            int e = task / 336, q = task % 336, t = q / NG, g = q % NG;
            int ch0 = (g == 0) ? 0 : (g == 1) ? 45 : 90 + 10 * (g - 2);
            int n = (g < 2) ? 45 : 10;
            float s = 0.f, qq = 0.f;
            for (int i = 0; i < n; ++i){ float vv = tile[e][t][ch0 + i]; s += vv; qq += vv * vv; }
            atomicAdd(&sgs[g], s);
            atomicAdd(&sgq[g], qq);
        }
        for (int task = tid; task < 1344; task += 512){
            int e = task / 672, q = task % 672, t = q / 28, c = q % 28;
            int eabs = pp * 2 + e;
            const float* src = &tile[e][t][c * 8];
            if (MODE == 1){
                bf16x8 h8, l8;
                #pragma unroll
                for (int j = 0; j < 8; ++j){ short hi, lo; split2(src[j], hi, lo); h8[j] = hi; l8[j] = lo; }
                size_t tix = (size_t)blk * NWIN + t;
                size_t base = (tix * 14 + (size_t)(c >> 2) * 2) * 512 + (size_t)(eabs + 16 * (c & 3)) * 8;
                *(bf16x8*)&planes[base] = h8;
                *(bf16x8*)&planes[base + 512] = l8;
            } else {
                if (c < 27){
                    size_t rbase = ((size_t)(blk * NWIN + t) * 16 + eabs) * FROW + c * 8;
                    *(float4*)&feat32[rbase] = *(const float4*)&src[0];
                    if (c < 26) *(float4*)&feat32[rbase + 4] = *(const float4*)&src[4];
                }
            }
        }
        __syncthreads();
    }
    if (tid < NG){
        atomicAdd(&accum[tid], sgs[tid]);
        atomicAdd(&accum[NG + tid], sgq[tid]);
    }
}

// ---------------------------------------------------------------------------
// prep: BN scale fold into Wih0 (hi-only bf16, RNE) + hidden weights bf16,
// all in MFMA B-fragment layout; bf0 = bih0 + Wih0 @ shift.
// ---------------------------------------------------------------------------
__global__ __launch_bounds__(256)
void prep_kernel(const float* __restrict__ Wih0, const float* __restrict__ Whh0,
                 const float* __restrict__ Wih1, const float* __restrict__ Whh1,
                 const float* __restrict__ bih0, const float* __restrict__ accum,
                 const float* __restrict__ conv_w, const float* __restrict__ bn_gamma,
                 const float* __restrict__ bn_beta,
                 short* __restrict__ WHh, short* __restrict__ W0h, float* __restrict__ bf0)
{
    __shared__ float scs[NG], shs[NG];
    int tid = threadIdx.x;
    if (tid < NG){
        float N = (tid < 2) ? 4096.f * NPAIR * NWIN : 4096.f * NF * NWIN;
        float m = accum[tid] / N;
        float v = accum[NG + tid] / N - m * m;
        float cw = conv_w[0];
        float A = bn_gamma[tid] * rsqrtf(cw * cw * v + 1e-5f);
        scs[tid] = A * cw;
        shs[tid] = bn_beta[tid] - A * cw * m;
    }
    __syncthreads();
    const int NH = 3 * 2 * 12 * 64 * 8;    // 36864
    const int N0 = 7 * 12 * 64 * 8;        // 43008
    for (int i = blockIdx.x * 256 + tid; i < NH + N0; i += gridDim.x * 256){
        if (i < NH){
            int j = i & 7, lane = (i >> 3) & 63, rest = i >> 9;
            int ct = rest % 12; rest /= 12;
            int ks = rest & 1, m = rest >> 1;
            int gg = ct * 16 + (lane & 15);
            int k = ks * 32 + ((lane >> 4) << 3) + j;
            const float* Wm = (m == 0) ? Whh0 : (m == 1) ? Wih1 : Whh1;
            WHh[i] = bf16rne(Wm[gg * HID + k]);
        } else {
            int e2 = i - NH;
            int j = e2 & 7, lane = (e2 >> 3) & 63, rest = e2 >> 9;
            int ct = rest % 12, ks = rest / 12;
            int gg = ct * 16 + (lane & 15);
            int k = ks * 32 + ((lane >> 4) << 3) + j;
            float v = (k < DIN) ? Wih0[gg * DIN + k] * scs[grp_of(k)] : 0.f;
            W0h[e2] = bf16rne(v);
        }
    }
    if (blockIdx.x == 0 && tid < GATES){
        float s = bih0[tid];
        for (int k = 0; k < DIN; ++k) s += Wih0[tid * DIN + k] * shs[grp_of(k)];
        bf0[tid] = s;
    }
}

// ---------------------------------------------------------------------------
// rec: 256 blocks x 512 thr. Waves 0-3 = MFMA only (all weights VGPR-resident,
// 2-pass A(hi+lo) x B(hi)). Waves 4-7 = helpers: stage feat frags + all
// pointwise (fast exp2 activations), h state in helper registers.
// ---------------------------------------------------------------------------
template<int MODE>
__device__ __forceinline__ void stage_fa(short (*fab)[64][8], int tix,
                                         const short* __restrict__ planes,
                                         const float* __restrict__ feat32, int ht)
{
    if (MODE == 1){
        for (int q = ht; q < 896; q += 256){
            int f = q >> 6, lane = q & 63;
            *(bf16x8*)&fab[f][lane][0] =
                *(const bf16x8*)&planes[((size_t)tix * 14 + f) * 512 + (size_t)lane * 8];
        }
    } else {
        for (int q = ht; q < 448; q += 256){
            int c = q >> 4, e = q & 15;
            float vv[8];
            const float* src = &feat32[((size_t)tix * 16 + e) * FROW + c * 8];
            if (c < 26){
                float4 u0 = *(const float4*)src, u1 = *(const float4*)(src + 4);
                vv[0]=u0.x; vv[1]=u0.y; vv[2]=u0.z; vv[3]=u0.w;
                vv[4]=u1.x; vv[5]=u1.y; vv[6]=u1.z; vv[7]=u1.w;
            } else if (c == 26){
                float4 u0 = *(const float4*)src;
                vv[0]=u0.x; vv[1]=u0.y; vv[2]=u0.z; vv[3]=u0.w;
                vv[4]=0.f; vv[5]=0.f; vv[6]=0.f; vv[7]=0.f;
            } else {
                #pragma unroll
                for (int j = 0; j < 8; ++j) vv[j] = 0.f;
            }
            bf16x8 h8, l8;
            #pragma unroll
            for (int j = 0; j < 8; ++j){ short hi, lo; split2(vv[j], hi, lo); h8[j] = hi; l8[j] = lo; }
            *(bf16x8*)&fab[(c >> 2) * 2 + 0][e + 16 * (c & 3)][0] = h8;
            *(bf16x8*)&fab[(c >> 2) * 2 + 1][e + 16 * (c & 3)][0] = l8;
        }
    }
}

template<int MODE>
__global__ __launch_bounds__(512, 2)
void rec_kernel(const short* __restrict__ planes, const float* __restrict__ feat32,
                const short* __restrict__ WHh, const short* __restrict__ W0h,
                const float* __restrict__ bf0, const float* __restrict__ bhh0,
                const float* __restrict__ bih1, const float* __restrict__ bhh1,
                float* __restrict__ out)
{
    __shared__ __align__(16) short fa[2][14][64][8];   // 28.7 KB
    __shared__ __align__(16) short hp[4][16][72];      // 9.2 KB
    __shared__ float aar[4][16][68];                   // 17.4 KB
    int tid = threadIdx.x;
    int w = tid >> 6, l = tid & 63;
    int blk = blockIdx.x;

    for (int i = tid; i < 4 * 16 * 72; i += 512) ((short*)hp)[i] = 0;

    if (w < 4){
        int lm = l & 15, kb = l >> 4;
        int jc = w * 16 + lm;
        bf16x8 WH_[3][2][3];
        #pragma unroll
        for (int m = 0; m < 3; ++m)
            #pragma unroll
            for (int ks = 0; ks < 2; ++ks)
                #pragma unroll
                for (int ro = 0; ro < 3; ++ro)
                    WH_[m][ks][ro] = *(const bf16x8*)&WHh[((((m * 2 + ks) * 12) + (ro * 4 + w)) * 64 + l) * 8];
        bf16x8 W0_[7][3];
        #pragma unroll
        for (int ks = 0; ks < 7; ++ks)
            #pragma unroll
            for (int ro = 0; ro < 3; ++ro)
                W0_[ks][ro] = *(const bf16x8*)&W0h[(((ks * 12) + (ro * 4 + w)) * 64 + l) * 8];

        float cr0 = bf0[jc]       + bhh0[jc];
        float cz0 = bf0[jc + 64]  + bhh0[jc + 64];
        float cin0 = bf0[jc + 128];
        float chn0 = bhh0[jc + 128];
        float cr1 = bih1[jc]      + bhh1[jc];
        float cz1 = bih1[jc + 64] + bhh1[jc + 64];
        float cin1 = bih1[jc + 128];
        float chn1 = bhh1[jc + 128];

        __syncthreads();   // P0
        #pragma unroll 1
        for (int t = 0; t < NWIN; ++t){
            int buf = t & 1;
            bf16x8 h0h[2], h0l[2], h1h[2], h1l[2];
            #pragma unroll
            for (int ks = 0; ks < 2; ++ks){
                int off = ks * 32 + kb * 8;
                h0h[ks] = *(const bf16x8*)&hp[0][lm][off];
                h0l[ks] = *(const bf16x8*)&hp[1][lm][off];
                h1h[ks] = *(const bf16x8*)&hp[2][lm][off];
                h1l[ks] = *(const bf16x8*)&hp[3][lm][off];
            }
            f32x4 ar0 = {cr0, cr0, cr0, cr0};
            f32x4 az0 = {cz0, cz0, cz0, cz0};
            f32x4 ain0 = {cin0, cin0, cin0, cin0};
            f32x4 ahn0 = {chn0, chn0, chn0, chn0};
            f32x4 ar1 = {cr1, cr1, cr1, cr1};
            f32x4 az1 = {cz1, cz1, cz1, cz1};
            f32x4 ahn1 = {chn1, chn1, chn1, chn1};
            #pragma unroll
            for (int ks = 0; ks < 2; ++ks){
                ar0 = MFMA(h0h[ks], WH_[0][ks][0], ar0);  ar0 = MFMA(h0l[ks], WH_[0][ks][0], ar0);
                az0 = MFMA(h0h[ks], WH_[0][ks][1], az0);  az0 = MFMA(h0l[ks], WH_[0][ks][1], az0);
                ahn0 = MFMA(h0h[ks], WH_[0][ks][2], ahn0); ahn0 = MFMA(h0l[ks], WH_[0][ks][2], ahn0);
                ar1 = MFMA(h1h[ks], WH_[2][ks][0], ar1);  ar1 = MFMA(h1l[ks], WH_[2][ks][0], ar1);
                az1 = MFMA(h1h[ks], WH_[2][ks][1], az1);  az1 = MFMA(h1l[ks], WH_[2][ks][1], az1);
                ahn1 = MFMA(h1h[ks], WH_[2][ks][2], ahn1); ahn1 = MFMA(h1l[ks], WH_[2][ks][2], ahn1);
            }
            #pragma unroll
            for (int ks = 0; ks < 7; ++ks){
                bf16x8 Fh = *(const bf16x8*)&fa[buf][ks * 2 + 0][l][0];
                bf16x8 Fl = *(const bf16x8*)&fa[buf][ks * 2 + 1][l][0];
                ar0 = MFMA(Fh, W0_[ks][0], ar0);  ar0 = MFMA(Fl, W0_[ks][0], ar0);
                az0 = MFMA(Fh, W0_[ks][1], az0);  az0 = MFMA(Fl, W0_[ks][1], az0);
                ain0 = MFMA(Fh, W0_[ks][2], ain0); ain0 = MFMA(Fl, W0_[ks][2], ain0);
            }
            #pragma unroll
            for (int i = 0; i < 4; ++i){
                int row = kb * 4 + i;
                aar[0][row][jc] = ar0[i];
                aar[1][row][jc] = az0[i];
                aar[2][row][jc] = ain0[i];
                aar[3][row][jc] = ahn0[i];
            }
            __syncthreads();   // B1
            __syncthreads();   // B2 (pointwise l0 done)
            bf16x8 n0h[2], n0l[2];
            #pragma unroll
            for (int ks = 0; ks < 2; ++ks){
                int off = ks * 32 + kb * 8;
                n0h[ks] = *(const bf16x8*)&hp[0][lm][off];
                n0l[ks] = *(const bf16x8*)&hp[1][lm][off];
            }
            f32x4 ain1 = {cin1, cin1, cin1, cin1};
            #pragma unroll
            for (int ks = 0; ks < 2; ++ks){
                ar1 = MFMA(n0h[ks], WH_[1][ks][0], ar1);  ar1 = MFMA(n0l[ks], WH_[1][ks][0], ar1);
                az1 = MFMA(n0h[ks], WH_[1][ks][1], az1);  az1 = MFMA(n0l[ks], WH_[1][ks][1], az1);
                ain1 = MFMA(n0h[ks], WH_[1][ks][2], ain1); ain1 = MFMA(n0l[ks], WH_[1][ks][2], ain1);
            }
            #pragma unroll
            for (int i = 0; i < 4; ++i){
                int row = kb * 4 + i;
                aar[0][row][jc] = ar1[i];
                aar[1][row][jc] = az1[i];
                aar[2][row][jc] = ain1[i];
                aar[3][row][jc] = ahn1[i];
            }
            __syncthreads();   // B3
            __syncthreads();   // B4 (pointwise l1 done)
        }
    } else {
        int ht = tid - 256;
        int j = ht & 63, rr = ht >> 6;
        float h0r[4] = {0.f, 0.f, 0.f, 0.f};
        float h1r[4] = {0.f, 0.f, 0.f, 0.f};
        stage_fa<MODE>(fa[0], blk * NWIN + 0, planes, feat32, ht);
        __syncthreads();   // P0
        #pragma unroll 1
        for (int t = 0; t < NWIN; ++t){
            int buf = t & 1;
            if (t < NWIN - 1) stage_fa<MODE>(fa[buf ^ 1], blk * NWIN + t + 1, planes, feat32, ht);
            __syncthreads();   // B1
            #pragma unroll
            for (int i = 0; i < 4; ++i){
                int row = rr + i * 4;
                float a  = aar[0][row][j], z_ = aar[1][row][j];
                float in_ = aar[2][row][j], hn = aar[3][row][j];
                float rg = sigm(a), zg = sigm(z_);
                float nn = tanhfast(in_ + rg * hn);
                float h = (1.f - zg) * nn + zg * h0r[i];
                h0r[i] = h;
                short hi, lo; split2(h, hi, lo);
                hp[0][row][j] = hi;
                hp[1][row][j] = lo;
            }
            __syncthreads();   // B2
            __syncthreads();   // B3
            #pragma unroll
            for (int i = 0; i < 4; ++i){
                int row = rr + i * 4;
                float a  = aar[0][row][j], z_ = aar[1][row][j];
                float in_ = aar[2][row][j], hn = aar[3][row][j];
                float rg = sigm(a), zg = sigm(z_);
                float nn = tanhfast(in_ + rg * hn);
                float h = (1.f - zg) * nn + zg * h1r[i];
                h1r[i] = h;
                short hi, lo; split2(h, hi, lo);
                hp[2][row][j] = hi;
                hp[3][row][j] = lo;
            }
            __syncthreads();   // B4
        }
        #pragma unroll
        for (int i = 0; i < 4; ++i)
            out[((size_t)(blk * 16) + rr + i * 4) * HID + j] = h1r[i];
    }
}

// ---------------------------------------------------------------------------
extern "C" void kernel_launch(void* const* d_in, const int* in_sizes, int n_in,
                              void* d_out, int out_size, void* d_ws, size_t ws_size,
                              hipStream_t stream) {
    const float* data     = (const float*)d_in[0];
    const float* conv_w   = (const float*)d_in[1];
    const float* bn_gamma = (const float*)d_in[3];
    const float* bn_beta  = (const float*)d_in[4];
    const float* Wih0     = (const float*)d_in[5];
    const float* Whh0     = (const float*)d_in[6];
    const float* bih0     = (const float*)d_in[7];
    const float* bhh0     = (const float*)d_in[8];
    const float* Wih1     = (const float*)d_in[9];
    const float* Whh1     = (const float*)d_in[10];
    const float* bih1     = (const float*)d_in[11];
    const float* bhh1     = (const float*)d_in[12];
    const int*  comb_a    = (const int*)d_in[13];
    const int*  comb_b    = (const int*)d_in[14];
    float* out = (float*)d_out;

    char* ws = (char*)d_ws;
    const size_t planes_bytes = (size_t)NGRP * NWIN * 14 * 512 * 2;          // 88,080,384
    const size_t feat32_bytes = (size_t)NGRP * NWIN * 16 * FROW * 4;         // 83,361,792
    const size_t WH_BYTES = 3 * 2 * 12 * 64 * 8 * 2;                          // 73,728
    const size_t W0_BYTES = 7 * 12 * 64 * 8 * 2;                              // 86,016
    size_t need1 = planes_bytes + WH_BYTES + W0_BYTES + 1024 + 256;
    bool mode1 = (ws_size >= need1);
    size_t big = mode1 ? planes_bytes : feat32_bytes;

    short* planes = (short*)ws;
    float* feat32 = (float*)ws;
    short* WHh = (short*)(ws + big);
    short* W0h = (short*)(ws + big + WH_BYTES);
    float* bf0 = (float*)(ws + big + WH_BYTES + W0_BYTES);
    float* accum = (float*)(ws + big + WH_BYTES + W0_BYTES + 1024);

    hipMemsetAsync(accum, 0, 2 * NG * sizeof(float), stream);
    if (mode1)
        stats_kernel<1><<<NGRP, 512, 0, stream>>>(data, comb_a, comb_b, planes, feat32, accum);
    else
        stats_kernel<0><<<NGRP, 512, 0, stream>>>(data, comb_a, comb_b, planes, feat32, accum);
    prep_kernel<<<64, 256, 0, stream>>>(Wih0, Whh0, Wih1, Whh1, bih0, accum,
                                        conv_w, bn_gamma, bn_beta, WHh, W0h, bf0);
    if (mode1)
        rec_kernel<1><<<NGRP, 512, 0, stream>>>(planes, feat32, WHh, W0h, bf0,
                                                bhh0, bih1, bhh1, out);
    else
        rec_kernel<0><<<NGRP, 512, 0, stream>>>(planes, feat32, WHh, W0h, bf0,
                                                bhh0, bih1, bhh1, out);
}

// Round 5
// 215.625 us; speedup vs baseline: 4.8047x; 1.0913x over previous
//
#include <hip/hip_runtime.h>
#include <math.h>

#define NF 10
#define TLEN 480
#define NWIN 24
#define WLEN 20
#define HID 64
#define NPAIR 45
#define DIN 210
#define NG 14
#define GATES 192
#define NGRP 256            // 4096 / 16 rows per group
#define FROW 212            // fp32 feat row length (53 float4)

typedef __attribute__((ext_vector_type(8))) short bf16x8;
typedef __attribute__((ext_vector_type(4))) float f32x4;

#define MFMA(a,b,c) __builtin_amdgcn_mfma_f32_16x16x32_bf16((a),(b),(c),0,0,0)

__device__ __forceinline__ int grp_of(int k){ return (k < 90) ? (k / 45) : 2 + (k - 90) / 10; }

__device__ __forceinline__ void split2(float x, short& hi, short& lo){
    unsigned u = __float_as_uint(x);
    hi = (short)(u >> 16);
    float hf = __uint_as_float(u & 0xffff0000u);
    lo = (short)(__float_as_uint(x - hf) >> 16);
}
__device__ __forceinline__ short bf16rne(float x){
    unsigned u = __float_as_uint(x);
    u += 0x7fffu + ((u >> 16) & 1u);
    return (short)(u >> 16);
}
__device__ __forceinline__ float sigm(float x){
    return __builtin_amdgcn_rcpf(1.f + __builtin_amdgcn_exp2f(x * -1.4426950408889634f));
}
__device__ __forceinline__ float tanhfast(float x){
    return 1.f - 2.f * __builtin_amdgcn_rcpf(1.f + __builtin_amdgcn_exp2f(x * 2.8853900817779268f));
}

// ---------------------------------------------------------------------------
// stats: one block per batch element (4096 blocks, 256 thr, ~41KB LDS ->
// 3 blocks/CU). Fused BN partial sums. Coalesced fp32 row writes in the
// rec-group layout feat32[grp][t][e][FROW].
// ---------------------------------------------------------------------------
__global__ __launch_bounds__(256)
void stats_kernel(const float* __restrict__ data, const int* __restrict__ comb_a,
                  const int* __restrict__ comb_b, float* __restrict__ feat32,
                  float* __restrict__ accum)
{
    __shared__ __align__(16) float xs[NF * TLEN];       // 19.2 KB
    __shared__ __align__(16) float tile[NWIN][FROW];    // 20.35 KB
    __shared__ float mean_s[240], std_s[240];
    __shared__ float sgs[NG], sgq[NG];
    int b = blockIdx.x, tid = threadIdx.x;

    const float* src = data + (size_t)b * (NF * TLEN);
    for (int q = tid; q < 1200; q += 256)
        *(float4*)&xs[q * 4] = *(const float4*)&src[q * 4];
    if (tid < NG){ sgs[tid] = 0.f; sgq[tid] = 0.f; }
    if (tid < 48) tile[tid / 2][210 + (tid & 1)] = 0.f;   // zero pad cols
    __syncthreads();

    if (tid < 240){
        int f = tid / NWIN, nw = tid % NWIN;
        float v[WLEN];
        {
            const float4* p4 = (const float4*)&xs[f * TLEN + nw * WLEN];
            #pragma unroll
            for (int i = 0; i < 5; ++i){
                float4 u = p4[i];
                v[i * 4 + 0] = u.x; v[i * 4 + 1] = u.y;
                v[i * 4 + 2] = u.z; v[i * 4 + 3] = u.w;
            }
        }
        float sum = 0.f, minv = v[0], wsum = 0.f;
        #pragma unroll
        for (int i = 0; i < WLEN; ++i){
            sum += v[i];
            minv = fminf(minv, v[i]);
            wsum += v[i] * ((float)(i + 1) * (1.0f / 210.0f));
        }
        float mean = sum * (1.0f / WLEN);
        float var = 0.f, m3 = 0.f, m4 = 0.f;
        #pragma unroll
        for (int i = 0; i < WLEN; ++i){
            float c = v[i] - mean, c2 = c * c;
            var += c2; m3 += c2 * c; m4 += c2 * c2;
        }
        var *= 0.05f; m3 *= 0.05f; m4 *= 0.05f;
        float sd = sqrtf(var);
        // stable-rank median via 190 pairwise comparisons
        int rk[WLEN];
        #pragma unroll
        for (int i = 0; i < WLEN; ++i) rk[i] = 0;
        #pragma unroll
        for (int i = 0; i < WLEN; ++i)
            #pragma unroll
            for (int jj = i + 1; jj < WLEN; ++jj){
                bool c = v[jj] < v[i];
                rk[i] += c ? 1 : 0;
                rk[jj] += c ? 0 : 1;
            }
        float med_lo = 0.f, med_hi = 0.f;
        #pragma unroll
        for (int i = 0; i < WLEN; ++i){
            if (rk[i] == 9)  med_lo = v[i];
            if (rk[i] == 10) med_hi = v[i];
        }
        float median = 0.5f * (med_lo + med_hi);
        float ratio = v[WLEN - 1] / (v[0] + 0.01f) - 1.0f;
        float s3 = sd * sd * sd;
        tile[nw][ 90 + f] = sd;
        tile[nw][100 + f] = mean / (sd + 0.01f);
        tile[nw][110 + f] = ratio;
        tile[nw][120 + f] = wsum;
        tile[nw][130 + f] = mean;
        tile[nw][140 + f] = minv;
        tile[nw][150 + f] = var;
        tile[nw][160 + f] = sum;
        tile[nw][170 + f] = median;
        tile[nw][180 + f] = m3 / (s3 + 0.01f);
        tile[nw][190 + f] = m4 / (s3 * sd + 0.01f) - 3.0f;
        tile[nw][200 + f] = sum;
        mean_s[f * NWIN + nw] = mean;
        std_s[f * NWIN + nw] = sd;
    }
    __syncthreads();

    for (int task = tid; task < NPAIR * NWIN; task += 256){
        int pi = task / NWIN, nw = task % NWIN;
        int fa_ = comb_a[pi], fb_ = comb_b[pi];
        float ma = mean_s[fa_ * NWIN + nw], mb = mean_s[fb_ * NWIN + nw];
        float sa = std_s[fa_ * NWIN + nw], sb = std_s[fb_ * NWIN + nw];
        const float* pa = &xs[fa_ * TLEN + nw * WLEN];
        const float* pb = &xs[fb_ * TLEN + nw * WLEN];
        float s = 0.f;
        #pragma unroll
        for (int i = 0; i < WLEN; ++i) s += (pa[i] - ma) * (pb[i] - mb);
        float cov = s * (1.0f / (WLEN - 1));
        tile[nw][pi] = cov / (sa * sb + 0.01f);
        tile[nw][NPAIR + pi] = cov;
    }
    __syncthreads();

    // fused BN partial sums
    for (int task = tid; task < NWIN * NG; task += 256){
        int g = task % NG, t = task / NG;
        int ch0 = (g == 0) ? 0 : (g == 1) ? 45 : 90 + 10 * (g - 2);
        int n = (g < 2) ? 45 : 10;
        float s = 0.f, q = 0.f;
        for (int i = 0; i < n; ++i){ float vv = tile[t][ch0 + i]; s += vv; q += vv * vv; }
        atomicAdd(&sgs[g], s);
        atomicAdd(&sgq[g], q);
    }
    __syncthreads();
    if (tid < NG){
        atomicAdd(&accum[tid], sgs[tid]);
        atomicAdd(&accum[NG + tid], sgq[tid]);
    }
    // coalesced row writes: [grp][t][e][FROW]
    int grp = b >> 4, e = b & 15;
    for (int q = tid; q < NWIN * 53; q += 256){
        int t = q / 53, c = (q % 53) * 4;
        size_t rbase = (((size_t)grp * NWIN + t) * 16 + e) * FROW + c;
        *(float4*)&feat32[rbase] = *(const float4*)&tile[t][c];
    }
}

// ---------------------------------------------------------------------------
// prep: BN scale fold into Wih0 (bf16 RNE) + hidden weights bf16, MFMA
// B-fragment layout; bf0 = bih0 + Wih0 @ shift.
// ---------------------------------------------------------------------------
__global__ __launch_bounds__(256)
void prep_kernel(const float* __restrict__ Wih0, const float* __restrict__ Whh0,
                 const float* __restrict__ Wih1, const float* __restrict__ Whh1,
                 const float* __restrict__ bih0, const float* __restrict__ accum,
                 const float* __restrict__ conv_w, const float* __restrict__ bn_gamma,
                 const float* __restrict__ bn_beta,
                 short* __restrict__ WHh, short* __restrict__ W0h, float* __restrict__ bf0)
{
    __shared__ float scs[NG], shs[NG];
    int tid = threadIdx.x;
    if (tid < NG){
        float N = (tid < 2) ? 4096.f * NPAIR * NWIN : 4096.f * NF * NWIN;
        float m = accum[tid] / N;
        float v = accum[NG + tid] / N - m * m;
        float cw = conv_w[0];
        float A = bn_gamma[tid] * rsqrtf(cw * cw * v + 1e-5f);
        scs[tid] = A * cw;
        shs[tid] = bn_beta[tid] - A * cw * m;
    }
    __syncthreads();
    const int NH = 3 * 2 * 12 * 64 * 8;    // 36864
    const int N0 = 7 * 12 * 64 * 8;        // 43008
    for (int i = blockIdx.x * 256 + tid; i < NH + N0; i += gridDim.x * 256){
        if (i < NH){
            int j = i & 7, lane = (i >> 3) & 63, rest = i >> 9;
            int ct = rest % 12; rest /= 12;
            int ks = rest & 1, m = rest >> 1;
            int gg = ct * 16 + (lane & 15);
            int k = ks * 32 + ((lane >> 4) << 3) + j;
            const float* Wm = (m == 0) ? Whh0 : (m == 1) ? Wih1 : Whh1;
            WHh[i] = bf16rne(Wm[gg * HID + k]);
        } else {
            int e2 = i - NH;
            int j = e2 & 7, lane = (e2 >> 3) & 63, rest = e2 >> 9;
            int ct = rest % 12, ks = rest / 12;
            int gg = ct * 16 + (lane & 15);
            int k = ks * 32 + ((lane >> 4) << 3) + j;
            float v = (k < DIN) ? Wih0[gg * DIN + k] * scs[grp_of(k)] : 0.f;
            W0h[e2] = bf16rne(v);
        }
    }
    if (blockIdx.x == 0 && tid < GATES){
        float s = bih0[tid];
        for (int k = 0; k < DIN; ++k) s += Wih0[tid * DIN + k] * shs[grp_of(k)];
        bf0[tid] = s;
    }
}

// ---------------------------------------------------------------------------
// rec: 256 blocks x 512 thr. Waves 0-3 = MFMA only (weights VGPR-resident,
// 2-pass A(hi+lo) x B(hi)). Waves 4-7 = helpers: stage+split feat rows into
// fragment LDS + all pointwise (fast exp2), h state in helper registers.
// ---------------------------------------------------------------------------
__device__ __forceinline__ void stage_fa(short (*fab)[64][8], int tix,
                                         const float* __restrict__ feat32, int ht)
{
    for (int q = ht; q < 448; q += 256){
        int c = q >> 4, e = q & 15;
        float vv[8];
        const float* src = &feat32[((size_t)tix * 16 + e) * FROW + c * 8];
        if (c < 26){
            float4 u0 = *(const float4*)src, u1 = *(const float4*)(src + 4);
            vv[0]=u0.x; vv[1]=u0.y; vv[2]=u0.z; vv[3]=u0.w;
            vv[4]=u1.x; vv[5]=u1.y; vv[6]=u1.z; vv[7]=u1.w;
        } else if (c == 26){
            float4 u0 = *(const float4*)src;
            vv[0]=u0.x; vv[1]=u0.y; vv[2]=u0.z; vv[3]=u0.w;
            vv[4]=0.f; vv[5]=0.f; vv[6]=0.f; vv[7]=0.f;
        } else {
            #pragma unroll
            for (int j = 0; j < 8; ++j) vv[j] = 0.f;
        }
        bf16x8 h8, l8;
        #pragma unroll
        for (int j = 0; j < 8; ++j){ short hi, lo; split2(vv[j], hi, lo); h8[j] = hi; l8[j] = lo; }
        *(bf16x8*)&fab[(c >> 2) * 2 + 0][e + 16 * (c & 3)][0] = h8;
        *(bf16x8*)&fab[(c >> 2) * 2 + 1][e + 16 * (c & 3)][0] = l8;
    }
}

__global__ __launch_bounds__(512, 2)
void rec_kernel(const float* __restrict__ feat32,
                const short* __restrict__ WHh, const short* __restrict__ W0h,
                const float* __restrict__ bf0, const float* __restrict__ bhh0,
                const float* __restrict__ bih1, const float* __restrict__ bhh1,
                float* __restrict__ out)
{
    __shared__ __align__(16) short fa[2][14][64][8];   // 28.7 KB
    __shared__ __align__(16) short hp[4][16][72];      // 9.2 KB
    __shared__ float aar[4][16][68];                   // 17.4 KB
    int tid = threadIdx.x;
    int w = tid >> 6, l = tid & 63;
    int blk = blockIdx.x;

    for (int i = tid; i < 4 * 16 * 72; i += 512) ((short*)hp)[i] = 0;

    if (w < 4){
        int lm = l & 15, kb = l >> 4;
        int jc = w * 16 + lm;
        bf16x8 WH_[3][2][3];
        #pragma unroll
        for (int m = 0; m < 3; ++m)
            #pragma unroll
            for (int ks = 0; ks < 2; ++ks)
                #pragma unroll
                for (int ro = 0; ro < 3; ++ro)
                    WH_[m][ks][ro] = *(const bf16x8*)&WHh[((((m * 2 + ks) * 12) + (ro * 4 + w)) * 64 + l) * 8];
        bf16x8 W0_[7][3];
        #pragma unroll
        for (int ks = 0; ks < 7; ++ks)
            #pragma unroll
            for (int ro = 0; ro < 3; ++ro)
                W0_[ks][ro] = *(const bf16x8*)&W0h[(((ks * 12) + (ro * 4 + w)) * 64 + l) * 8];

        float cr0 = bf0[jc]       + bhh0[jc];
        float cz0 = bf0[jc + 64]  + bhh0[jc + 64];
        float cin0 = bf0[jc + 128];
        float chn0 = bhh0[jc + 128];
        float cr1 = bih1[jc]      + bhh1[jc];
        float cz1 = bih1[jc + 64] + bhh1[jc + 64];
        float cin1 = bih1[jc + 128];
        float chn1 = bhh1[jc + 128];

        __syncthreads();   // P0
        #pragma unroll 1
        for (int t = 0; t < NWIN; ++t){
            int buf = t & 1;
            bf16x8 h0h[2], h0l[2], h1h[2], h1l[2];
            #pragma unroll
            for (int ks = 0; ks < 2; ++ks){
                int off = ks * 32 + kb * 8;
                h0h[ks] = *(const bf16x8*)&hp[0][lm][off];
                h0l[ks] = *(const bf16x8*)&hp[1][lm][off];
                h1h[ks] = *(const bf16x8*)&hp[2][lm][off];
                h1l[ks] = *(const bf16x8*)&hp[3][lm][off];
            }
            f32x4 ar0 = {cr0, cr0, cr0, cr0};
            f32x4 az0 = {cz0, cz0, cz0, cz0};
            f32x4 ain0 = {cin0, cin0, cin0, cin0};
            f32x4 ahn0 = {chn0, chn0, chn0, chn0};
            f32x4 ar1 = {cr1, cr1, cr1, cr1};
            f32x4 az1 = {cz1, cz1, cz1, cz1};
            f32x4 ahn1 = {chn1, chn1, chn1, chn1};
            #pragma unroll
            for (int ks = 0; ks < 2; ++ks){
                ar0 = MFMA(h0h[ks], WH_[0][ks][0], ar0);  ar0 = MFMA(h0l[ks], WH_[0][ks][0], ar0);
                az0 = MFMA(h0h[ks], WH_[0][ks][1], az0);  az0 = MFMA(h0l[ks], WH_[0][ks][1], az0);
                ahn0 = MFMA(h0h[ks], WH_[0][ks][2], ahn0); ahn0 = MFMA(h0l[ks], WH_[0][ks][2], ahn0);
                ar1 = MFMA(h1h[ks], WH_[2][ks][0], ar1);  ar1 = MFMA(h1l[ks], WH_[2][ks][0], ar1);
                az1 = MFMA(h1h[ks], WH_[2][ks][1], az1);  az1 = MFMA(h1l[ks], WH_[2][ks][1], az1);
                ahn1 = MFMA(h1h[ks], WH_[2][ks][2], ahn1); ahn1 = MFMA(h1l[ks], WH_[2][ks][2], ahn1);
            }
            #pragma unroll
            for (int ks = 0; ks < 7; ++ks){
                bf16x8 Fh = *(const bf16x8*)&fa[buf][ks * 2 + 0][l][0];
                bf16x8 Fl = *(const bf16x8*)&fa[buf][ks * 2 + 1][l][0];
                ar0 = MFMA(Fh, W0_[ks][0], ar0);  ar0 = MFMA(Fl, W0_[ks][0], ar0);
                az0 = MFMA(Fh, W0_[ks][1], az0);  az0 = MFMA(Fl, W0_[ks][1], az0);
                ain0 = MFMA(Fh, W0_[ks][2], ain0); ain0 = MFMA(Fl, W0_[ks][2], ain0);
            }
            #pragma unroll
            for (int i = 0; i < 4; ++i){
                int row = kb * 4 + i;
                aar[0][row][jc] = ar0[i];
                aar[1][row][jc] = az0[i];
                aar[2][row][jc] = ain0[i];
                aar[3][row][jc] = ahn0[i];
            }
            __syncthreads();   // B1
            __syncthreads();   // B2 (pointwise l0 done)
            bf16x8 n0h[2], n0l[2];
            #pragma unroll
            for (int ks = 0; ks < 2; ++ks){
                int off = ks * 32 + kb * 8;
                n0h[ks] = *(const bf16x8*)&hp[0][lm][off];
                n0l[ks] = *(const bf16x8*)&hp[1][lm][off];
            }
            f32x4 ain1 = {cin1, cin1, cin1, cin1};
            #pragma unroll
            for (int ks = 0; ks < 2; ++ks){
                ar1 = MFMA(n0h[ks], WH_[1][ks][0], ar1);  ar1 = MFMA(n0l[ks], WH_[1][ks][0], ar1);
                az1 = MFMA(n0h[ks], WH_[1][ks][1], az1);  az1 = MFMA(n0l[ks], WH_[1][ks][1], az1);
                ain1 = MFMA(n0h[ks], WH_[1][ks][2], ain1); ain1 = MFMA(n0l[ks], WH_[1][ks][2], ain1);
            }
            #pragma unroll
            for (int i = 0; i < 4; ++i){
                int row = kb * 4 + i;
                aar[0][row][jc] = ar1[i];
                aar[1][row][jc] = az1[i];
                aar[2][row][jc] = ain1[i];
                aar[3][row][jc] = ahn1[i];
            }
            __syncthreads();   // B3
            __syncthreads();   // B4 (pointwise l1 done)
        }
    } else {
        int ht = tid - 256;
        int j = ht & 63, rr = ht >> 6;
        float h0r[4] = {0.f, 0.f, 0.f, 0.f};
        float h1r[4] = {0.f, 0.f, 0.f, 0.f};
        stage_fa(fa[0], blk * NWIN + 0, feat32, ht);
        __syncthreads();   // P0
        #pragma unroll 1
        for (int t = 0; t < NWIN; ++t){
            int buf = t & 1;
            if (t < NWIN - 1) stage_fa(fa[buf ^ 1], blk * NWIN + t + 1, feat32, ht);
            __syncthreads();   // B1
            #pragma unroll
            for (int i = 0; i < 4; ++i){
                int row = rr + i * 4;
                float a  = aar[0][row][j], z_ = aar[1][row][j];
                float in_ = aar[2][row][j], hn = aar[3][row][j];
                float rg = sigm(a), zg = sigm(z_);
                float nn = tanhfast(in_ + rg * hn);
                float h = (1.f - zg) * nn + zg * h0r[i];
                h0r[i] = h;
                short hi, lo; split2(h, hi, lo);
                hp[0][row][j] = hi;
                hp[1][row][j] = lo;
            }
            __syncthreads();   // B2
            __syncthreads();   // B3
            #pragma unroll
            for (int i = 0; i < 4; ++i){
                int row = rr + i * 4;
                float a  = aar[0][row][j], z_ = aar[1][row][j];
                float in_ = aar[2][row][j], hn = aar[3][row][j];
                float rg = sigm(a), zg = sigm(z_);
                float nn = tanhfast(in_ + rg * hn);
                float h = (1.f - zg) * nn + zg * h1r[i];
                h1r[i] = h;
                short hi, lo; split2(h, hi, lo);
                hp[2][row][j] = hi;
                hp[3][row][j] = lo;
            }
            __syncthreads();   // B4
        }
        #pragma unroll
        for (int i = 0; i < 4; ++i)
            out[((size_t)(blk * 16) + rr + i * 4) * HID + j] = h1r[i];
    }
}

// ---------------------------------------------------------------------------
extern "C" void kernel_launch(void* const* d_in, const int* in_sizes, int n_in,
                              void* d_out, int out_size, void* d_ws, size_t ws_size,
                              hipStream_t stream) {
    const float* data     = (const float*)d_in[0];
    const float* conv_w   = (const float*)d_in[1];
    const float* bn_gamma = (const float*)d_in[3];
    const float* bn_beta  = (const float*)d_in[4];
    const float* Wih0     = (const float*)d_in[5];
    const float* Whh0     = (const float*)d_in[6];
    const float* bih0     = (const float*)d_in[7];
    const float* bhh0     = (const float*)d_in[8];
    const float* Wih1     = (const float*)d_in[9];
    const float* Whh1     = (const float*)d_in[10];
    const float* bih1     = (const float*)d_in[11];
    const float* bhh1     = (const float*)d_in[12];
    const int*  comb_a    = (const int*)d_in[13];
    const int*  comb_b    = (const int*)d_in[14];
    float* out = (float*)d_out;

    char* ws = (char*)d_ws;
    const size_t feat32_bytes = (size_t)NGRP * NWIN * 16 * FROW * 4;   // 83,361,792
    const size_t WH_BYTES = 3 * 2 * 12 * 64 * 8 * 2;                    // 73,728
    const size_t W0_BYTES = 7 * 12 * 64 * 8 * 2;                        // 86,016

    float* feat32 = (float*)ws;
    short* WHh = (short*)(ws + feat32_bytes);
    short* W0h = (short*)(ws + feat32_bytes + WH_BYTES);
    float* bf0 = (float*)(ws + feat32_bytes + WH_BYTES + W0_BYTES);
    float* accum = (float*)(ws + feat32_bytes + WH_BYTES + W0_BYTES + 1024);

    hipMemsetAsync(accum, 0, 2 * NG * sizeof(float), stream);
    stats_kernel<<<4096, 256, 0, stream>>>(data, comb_a, comb_b, feat32, accum);
    prep_kernel<<<64, 256, 0, stream>>>(Wih0, Whh0, Wih1, Whh1, bih0, accum,
                                        conv_w, bn_gamma, bn_beta, WHh, W0h, bf0);
    rec_kernel<<<NGRP, 512, 0, stream>>>(feat32, WHh, W0h, bf0,
                                         bhh0, bih1, bhh1, out);
}

// Round 7
// 213.259 us; speedup vs baseline: 4.8580x; 1.0111x over previous
//
#include <hip/hip_runtime.h>
#include <math.h>

#define NF 10
#define TLEN 480
#define NWIN 24
#define WLEN 20
#define HID 64
#define NPAIR 45
#define DIN 210
#define NG 14
#define GATES 192
#define NGRP 256            // 4096 / 16 rows per group
#define FROW 212            // fp32 feat row length (53 float4)

typedef __attribute__((ext_vector_type(8))) short bf16x8;
typedef __attribute__((ext_vector_type(4))) float f32x4;

#define MFMA(a,b,c) __builtin_amdgcn_mfma_f32_16x16x32_bf16((a),(b),(c),0,0,0)

__device__ __forceinline__ int grp_of(int k){ return (k < 90) ? (k / 45) : 2 + (k - 90) / 10; }

__device__ __forceinline__ void split2(float x, short& hi, short& lo){
    unsigned u = __float_as_uint(x);
    hi = (short)(u >> 16);
    float hf = __uint_as_float(u & 0xffff0000u);
    lo = (short)(__float_as_uint(x - hf) >> 16);
}
__device__ __forceinline__ short bf16rne(float x){
    unsigned u = __float_as_uint(x);
    u += 0x7fffu + ((u >> 16) & 1u);
    return (short)(u >> 16);
}
__device__ __forceinline__ float sigm(float x){
    return __builtin_amdgcn_rcpf(1.f + __builtin_amdgcn_exp2f(x * -1.4426950408889634f));
}
__device__ __forceinline__ float tanhfast(float x){
    return 1.f - 2.f * __builtin_amdgcn_rcpf(1.f + __builtin_amdgcn_exp2f(x * 2.8853900817779268f));
}

// ---------------------------------------------------------------------------
// stats v3b: one block per batch element; NO xs staging (direct global reads,
// L1/L2 served); raw-dot pair formula; ~24KB LDS -> 6 blocks/CU.
// Fused BN partial sums; coalesced row writes.
// FIX vs v3: comb staging predicate (tid<NPAIR, was tid in [240,285) > 256).
// ---------------------------------------------------------------------------
__global__ __launch_bounds__(256)
void stats_kernel(const float* __restrict__ data, const int* __restrict__ comb_a,
                  const int* __restrict__ comb_b, float* __restrict__ feat32,
                  float* __restrict__ accum)
{
    __shared__ __align__(16) float tile[NWIN][FROW];    // 20.35 KB
    __shared__ float mean_s[240], std_s[240];           // 1.9 KB
    __shared__ float sgs[NG], sgq[NG];
    __shared__ int ca_s[NPAIR], cb_s[NPAIR];
    int b = blockIdx.x, tid = threadIdx.x;
    const float* src = data + (size_t)b * (NF * TLEN);

    if (tid < NG){ sgs[tid] = 0.f; sgq[tid] = 0.f; }
    if (tid < NPAIR){ ca_s[tid] = comb_a[tid]; cb_s[tid] = comb_b[tid]; }
    if (tid >= 200 && tid < 248) tile[(tid - 200) / 2][210 + (tid & 1)] = 0.f; // zero pad cols

    if (tid < 240){
        int f = tid / NWIN, nw = tid % NWIN;
        float v[WLEN];
        {
            const float4* p4 = (const float4*)&src[f * TLEN + nw * WLEN];
            #pragma unroll
            for (int i = 0; i < 5; ++i){
                float4 u = p4[i];
                v[i * 4 + 0] = u.x; v[i * 4 + 1] = u.y;
                v[i * 4 + 2] = u.z; v[i * 4 + 3] = u.w;
            }
        }
        float sum = 0.f, minv = v[0], wsum = 0.f;
        #pragma unroll
        for (int i = 0; i < WLEN; ++i){
            sum += v[i];
            minv = fminf(minv, v[i]);
            wsum += v[i] * ((float)(i + 1) * (1.0f / 210.0f));
        }
        float mean = sum * (1.0f / WLEN);
        float var = 0.f, m3 = 0.f, m4 = 0.f;
        #pragma unroll
        for (int i = 0; i < WLEN; ++i){
            float c = v[i] - mean, c2 = c * c;
            var += c2; m3 += c2 * c; m4 += c2 * c2;
        }
        var *= 0.05f; m3 *= 0.05f; m4 *= 0.05f;
        float sd = sqrtf(var);
        // stable-rank median via 190 pairwise comparisons
        int rk[WLEN];
        #pragma unroll
        for (int i = 0; i < WLEN; ++i) rk[i] = 0;
        #pragma unroll
        for (int i = 0; i < WLEN; ++i)
            #pragma unroll
            for (int jj = i + 1; jj < WLEN; ++jj){
                bool c = v[jj] < v[i];
                rk[i] += c ? 1 : 0;
                rk[jj] += c ? 0 : 1;
            }
        float med_lo = 0.f, med_hi = 0.f;
        #pragma unroll
        for (int i = 0; i < WLEN; ++i){
            if (rk[i] == 9)  med_lo = v[i];
            if (rk[i] == 10) med_hi = v[i];
        }
        float median = 0.5f * (med_lo + med_hi);
        float ratio = v[WLEN - 1] / (v[0] + 0.01f) - 1.0f;
        float s3 = sd * sd * sd;
        tile[nw][ 90 + f] = sd;
        tile[nw][100 + f] = mean / (sd + 0.01f);
        tile[nw][110 + f] = ratio;
        tile[nw][120 + f] = wsum;
        tile[nw][130 + f] = mean;
        tile[nw][140 + f] = minv;
        tile[nw][150 + f] = var;
        tile[nw][160 + f] = sum;
        tile[nw][170 + f] = median;
        tile[nw][180 + f] = m3 / (s3 + 0.01f);
        tile[nw][190 + f] = m4 / (s3 * sd + 0.01f) - 3.0f;
        tile[nw][200 + f] = sum;
        mean_s[f * NWIN + nw] = mean;
        std_s[f * NWIN + nw] = sd;
    }
    __syncthreads();   // singles + combs staged

    // pairs: raw-dot from global (L1/L2-hot), 1 FMA/elem, no LDS inner reads
    for (int task = tid; task < NPAIR * NWIN; task += 256){
        int pi = task / NWIN, nw = task % NWIN;
        int fa_ = ca_s[pi], fb_ = cb_s[pi];
        const float4* pa4 = (const float4*)&src[fa_ * TLEN + nw * WLEN];
        const float4* pb4 = (const float4*)&src[fb_ * TLEN + nw * WLEN];
        float dot = 0.f;
        #pragma unroll
        for (int i = 0; i < 5; ++i){
            float4 a = pa4[i], bb = pb4[i];
            dot += a.x * bb.x + a.y * bb.y + a.z * bb.z + a.w * bb.w;
        }
        float ma = mean_s[fa_ * NWIN + nw], mb = mean_s[fb_ * NWIN + nw];
        float sa = std_s[fa_ * NWIN + nw], sb = std_s[fb_ * NWIN + nw];
        float cov = (dot - (float)WLEN * ma * mb) * (1.0f / (WLEN - 1));
        tile[nw][pi] = cov / (sa * sb + 0.01f);
        tile[nw][NPAIR + pi] = cov;
    }
    __syncthreads();   // tile complete

    // fused BN partial sums (reads tile)
    for (int task = tid; task < NWIN * NG; task += 256){
        int g = task % NG, t = task / NG;
        int ch0 = (g == 0) ? 0 : (g == 1) ? 45 : 90 + 10 * (g - 2);
        int n = (g < 2) ? 45 : 10;
        float s = 0.f, q = 0.f;
        for (int i = 0; i < n; ++i){ float vv = tile[t][ch0 + i]; s += vv; q += vv * vv; }
        atomicAdd(&sgs[g], s);
        atomicAdd(&sgq[g], q);
    }
    // coalesced row writes: [grp][t][e][FROW]  (reads tile, independent of BN)
    {
        int grp = b >> 4, e = b & 15;
        for (int q = tid; q < NWIN * 53; q += 256){
            int t = q / 53, c = (q % 53) * 4;
            size_t rbase = (((size_t)grp * NWIN + t) * 16 + e) * FROW + c;
            *(float4*)&feat32[rbase] = *(const float4*)&tile[t][c];
        }
    }
    __syncthreads();
    if (tid < NG){
        atomicAdd(&accum[tid], sgs[tid]);
        atomicAdd(&accum[NG + tid], sgq[tid]);
    }
}

// ---------------------------------------------------------------------------
// prep: BN scale fold into Wih0 (bf16 RNE) + hidden weights bf16, MFMA
// B-fragment layout; bf0 = bih0 + Wih0 @ shift.
// ---------------------------------------------------------------------------
__global__ __launch_bounds__(256)
void prep_kernel(const float* __restrict__ Wih0, const float* __restrict__ Whh0,
                 const float* __restrict__ Wih1, const float* __restrict__ Whh1,
                 const float* __restrict__ bih0, const float* __restrict__ accum,
                 const float* __restrict__ conv_w, const float* __restrict__ bn_gamma,
                 const float* __restrict__ bn_beta,
                 short* __restrict__ WHh, short* __restrict__ W0h, float* __restrict__ bf0)
{
    __shared__ float scs[NG], shs[NG];
    int tid = threadIdx.x;
    if (tid < NG){
        float N = (tid < 2) ? 4096.f * NPAIR * NWIN : 4096.f * NF * NWIN;
        float m = accum[tid] / N;
        float v = accum[NG + tid] / N - m * m;
        float cw = conv_w[0];
        float A = bn_gamma[tid] * rsqrtf(cw * cw * v + 1e-5f);
        scs[tid] = A * cw;
        shs[tid] = bn_beta[tid] - A * cw * m;
    }
    __syncthreads();
    const int NH = 3 * 2 * 12 * 64 * 8;    // 36864
    const int N0 = 7 * 12 * 64 * 8;        // 43008
    for (int i = blockIdx.x * 256 + tid; i < NH + N0; i += gridDim.x * 256){
        if (i < NH){
            int j = i & 7, lane = (i >> 3) & 63, rest = i >> 9;
            int ct = rest % 12; rest /= 12;
            int ks = rest & 1, m = rest >> 1;
            int gg = ct * 16 + (lane & 15);
            int k = ks * 32 + ((lane >> 4) << 3) + j;
            const float* Wm = (m == 0) ? Whh0 : (m == 1) ? Wih1 : Whh1;
            WHh[i] = bf16rne(Wm[gg * HID + k]);
        } else {
            int e2 = i - NH;
            int j = e2 & 7, lane = (e2 >> 3) & 63, rest = e2 >> 9;
            int ct = rest % 12, ks = rest / 12;
            int gg = ct * 16 + (lane & 15);
            int k = ks * 32 + ((lane >> 4) << 3) + j;
            float v = (k < DIN) ? Wih0[gg * DIN + k] * scs[grp_of(k)] : 0.f;
            W0h[e2] = bf16rne(v);
        }
    }
    if (blockIdx.x == 0 && tid < GATES){
        float s = bih0[tid];
        for (int k = 0; k < DIN; ++k) s += Wih0[tid * DIN + k] * shs[grp_of(k)];
        bf0[tid] = s;
    }
}

// ---------------------------------------------------------------------------
// rec: 256 blocks x 512 thr. Waves 0-3 = MFMA only (weights VGPR-resident,
// 2-pass A(hi+lo) x B(hi)). Waves 4-7 = helpers: stage+split feat rows into
// fragment LDS + all pointwise (fast exp2), h state in helper registers.
// ---------------------------------------------------------------------------
__device__ __forceinline__ void stage_fa(short (*fab)[64][8], int tix,
                                         const float* __restrict__ feat32, int ht)
{
    for (int q = ht; q < 448; q += 256){
        int c = q >> 4, e = q & 15;
        float vv[8];
        const float* src = &feat32[((size_t)tix * 16 + e) * FROW + c * 8];
        if (c < 26){
            float4 u0 = *(const float4*)src, u1 = *(const float4*)(src + 4);
            vv[0]=u0.x; vv[1]=u0.y; vv[2]=u0.z; vv[3]=u0.w;
            vv[4]=u1.x; vv[5]=u1.y; vv[6]=u1.z; vv[7]=u1.w;
        } else if (c == 26){
            float4 u0 = *(const float4*)src;
            vv[0]=u0.x; vv[1]=u0.y; vv[2]=u0.z; vv[3]=u0.w;
            vv[4]=0.f; vv[5]=0.f; vv[6]=0.f; vv[7]=0.f;
        } else {
            #pragma unroll
            for (int j = 0; j < 8; ++j) vv[j] = 0.f;
        }
        bf16x8 h8, l8;
        #pragma unroll
        for (int j = 0; j < 8; ++j){ short hi, lo; split2(vv[j], hi, lo); h8[j] = hi; l8[j] = lo; }
        *(bf16x8*)&fab[(c >> 2) * 2 + 0][e + 16 * (c & 3)][0] = h8;
        *(bf16x8*)&fab[(c >> 2) * 2 + 1][e + 16 * (c & 3)][0] = l8;
    }
}

__global__ __launch_bounds__(512, 2)
void rec_kernel(const float* __restrict__ feat32,
                const short* __restrict__ WHh, const short* __restrict__ W0h,
                const float* __restrict__ bf0, const float* __restrict__ bhh0,
                const float* __restrict__ bih1, const float* __restrict__ bhh1,
                float* __restrict__ out)
{
    __shared__ __align__(16) short fa[2][14][64][8];   // 28.7 KB
    __shared__ __align__(16) short hp[4][16][72];      // 9.2 KB
    __shared__ float aar[4][16][68];                   // 17.4 KB
    int tid = threadIdx.x;
    int w = tid >> 6, l = tid & 63;
    int blk = blockIdx.x;

    for (int i = tid; i < 4 * 16 * 72; i += 512) ((short*)hp)[i] = 0;

    if (w < 4){
        int lm = l & 15, kb = l >> 4;
        int jc = w * 16 + lm;
        bf16x8 WH_[3][2][3];
        #pragma unroll
        for (int m = 0; m < 3; ++m)
            #pragma unroll
            for (int ks = 0; ks < 2; ++ks)
                #pragma unroll
                for (int ro = 0; ro < 3; ++ro)
                    WH_[m][ks][ro] = *(const bf16x8*)&WHh[((((m * 2 + ks) * 12) + (ro * 4 + w)) * 64 + l) * 8];
        bf16x8 W0_[7][3];
        #pragma unroll
        for (int ks = 0; ks < 7; ++ks)
            #pragma unroll
            for (int ro = 0; ro < 3; ++ro)
                W0_[ks][ro] = *(const bf16x8*)&W0h[(((ks * 12) + (ro * 4 + w)) * 64 + l) * 8];

        float cr0 = bf0[jc]       + bhh0[jc];
        float cz0 = bf0[jc + 64]  + bhh0[jc + 64];
        float cin0 = bf0[jc + 128];
        float chn0 = bhh0[jc + 128];
        float cr1 = bih1[jc]      + bhh1[jc];
        float cz1 = bih1[jc + 64] + bhh1[jc + 64];
        float cin1 = bih1[jc + 128];
        float chn1 = bhh1[jc + 128];

        __syncthreads();   // P0
        #pragma unroll 1
        for (int t = 0; t < NWIN; ++t){
            int buf = t & 1;
            bf16x8 h0h[2], h0l[2], h1h[2], h1l[2];
            #pragma unroll
            for (int ks = 0; ks < 2; ++ks){
                int off = ks * 32 + kb * 8;
                h0h[ks] = *(const bf16x8*)&hp[0][lm][off];
                h0l[ks] = *(const bf16x8*)&hp[1][lm][off];
                h1h[ks] = *(const bf16x8*)&hp[2][lm][off];
                h1l[ks] = *(const bf16x8*)&hp[3][lm][off];
            }
            f32x4 ar0 = {cr0, cr0, cr0, cr0};
            f32x4 az0 = {cz0, cz0, cz0, cz0};
            f32x4 ain0 = {cin0, cin0, cin0, cin0};
            f32x4 ahn0 = {chn0, chn0, chn0, chn0};
            f32x4 ar1 = {cr1, cr1, cr1, cr1};
            f32x4 az1 = {cz1, cz1, cz1, cz1};
            f32x4 ahn1 = {chn1, chn1, chn1, chn1};
            #pragma unroll
            for (int ks = 0; ks < 2; ++ks){
                ar0 = MFMA(h0h[ks], WH_[0][ks][0], ar0);  ar0 = MFMA(h0l[ks], WH_[0][ks][0], ar0);
                az0 = MFMA(h0h[ks], WH_[0][ks][1], az0);  az0 = MFMA(h0l[ks], WH_[0][ks][1], az0);
                ahn0 = MFMA(h0h[ks], WH_[0][ks][2], ahn0); ahn0 = MFMA(h0l[ks], WH_[0][ks][2], ahn0);
                ar1 = MFMA(h1h[ks], WH_[2][ks][0], ar1);  ar1 = MFMA(h1l[ks], WH_[2][ks][0], ar1);
                az1 = MFMA(h1h[ks], WH_[2][ks][1], az1);  az1 = MFMA(h1l[ks], WH_[2][ks][1], az1);
                ahn1 = MFMA(h1h[ks], WH_[2][ks][2], ahn1); ahn1 = MFMA(h1l[ks], WH_[2][ks][2], ahn1);
            }
            #pragma unroll
            for (int ks = 0; ks < 7; ++ks){
                bf16x8 Fh = *(const bf16x8*)&fa[buf][ks * 2 + 0][l][0];
                bf16x8 Fl = *(const bf16x8*)&fa[buf][ks * 2 + 1][l][0];
                ar0 = MFMA(Fh, W0_[ks][0], ar0);  ar0 = MFMA(Fl, W0_[ks][0], ar0);
                az0 = MFMA(Fh, W0_[ks][1], az0);  az0 = MFMA(Fl, W0_[ks][1], az0);
                ain0 = MFMA(Fh, W0_[ks][2], ain0); ain0 = MFMA(Fl, W0_[ks][2], ain0);
            }
            #pragma unroll
            for (int i = 0; i < 4; ++i){
                int row = kb * 4 + i;
                aar[0][row][jc] = ar0[i];
                aar[1][row][jc] = az0[i];
                aar[2][row][jc] = ain0[i];
                aar[3][row][jc] = ahn0[i];
            }
            __syncthreads();   // B1
            __syncthreads();   // B2 (pointwise l0 done)
            bf16x8 n0h[2], n0l[2];
            #pragma unroll
            for (int ks = 0; ks < 2; ++ks){
                int off = ks * 32 + kb * 8;
                n0h[ks] = *(const bf16x8*)&hp[0][lm][off];
                n0l[ks] = *(const bf16x8*)&hp[1][lm][off];
            }
            f32x4 ain1 = {cin1, cin1, cin1, cin1};
            #pragma unroll
            for (int ks = 0; ks < 2; ++ks){
                ar1 = MFMA(n0h[ks], WH_[1][ks][0], ar1);  ar1 = MFMA(n0l[ks], WH_[1][ks][0], ar1);
                az1 = MFMA(n0h[ks], WH_[1][ks][1], az1);  az1 = MFMA(n0l[ks], WH_[1][ks][1], az1);
                ain1 = MFMA(n0h[ks], WH_[1][ks][2], ain1); ain1 = MFMA(n0l[ks], WH_[1][ks][2], ain1);
            }
            #pragma unroll
            for (int i = 0; i < 4; ++i){
                int row = kb * 4 + i;
                aar[0][row][jc] = ar1[i];
                aar[1][row][jc] = az1[i];
                aar[2][row][jc] = ain1[i];
                aar[3][row][jc] = ahn1[i];
            }
            __syncthreads();   // B3
            __syncthreads();   // B4 (pointwise l1 done)
        }
    } else {
        int ht = tid - 256;
        int j = ht & 63, rr = ht >> 6;
        float h0r[4] = {0.f, 0.f, 0.f, 0.f};
        float h1r[4] = {0.f, 0.f, 0.f, 0.f};
        stage_fa(fa[0], blk * NWIN + 0, feat32, ht);
        __syncthreads();   // P0
        #pragma unroll 1
        for (int t = 0; t < NWIN; ++t){
            int buf = t & 1;
            if (t < NWIN - 1) stage_fa(fa[buf ^ 1], blk * NWIN + t + 1, feat32, ht);
            __syncthreads();   // B1
            #pragma unroll
            for (int i = 0; i < 4; ++i){
                int row = rr + i * 4;
                float a  = aar[0][row][j], z_ = aar[1][row][j];
                float in_ = aar[2][row][j], hn = aar[3][row][j];
                float rg = sigm(a), zg = sigm(z_);
                float nn = tanhfast(in_ + rg * hn);
                float h = (1.f - zg) * nn + zg * h0r[i];
                h0r[i] = h;
                short hi, lo; split2(h, hi, lo);
                hp[0][row][j] = hi;
                hp[1][row][j] = lo;
            }
            __syncthreads();   // B2
            __syncthreads();   // B3
            #pragma unroll
            for (int i = 0; i < 4; ++i){
                int row = rr + i * 4;
                float a  = aar[0][row][j], z_ = aar[1][row][j];
                float in_ = aar[2][row][j], hn = aar[3][row][j];
                float rg = sigm(a), zg = sigm(z_);
                float nn = tanhfast(in_ + rg * hn);
                float h = (1.f - zg) * nn + zg * h1r[i];
                h1r[i] = h;
                short hi, lo; split2(h, hi, lo);
                hp[2][row][j] = hi;
                hp[3][row][j] = lo;
            }
            __syncthreads();   // B4
        }
        #pragma unroll
        for (int i = 0; i < 4; ++i)
            out[((size_t)(blk * 16) + rr + i * 4) * HID + j] = h1r[i];
    }
}

// ---------------------------------------------------------------------------
extern "C" void kernel_launch(void* const* d_in, const int* in_sizes, int n_in,
                              void* d_out, int out_size, void* d_ws, size_t ws_size,
                              hipStream_t stream) {
    const float* data     = (const float*)d_in[0];
    const float* conv_w   = (const float*)d_in[1];
    const float* bn_gamma = (const float*)d_in[3];
    const float* bn_beta  = (const float*)d_in[4];
    const float* Wih0     = (const float*)d_in[5];
    const float* Whh0     = (const float*)d_in[6];
    const float* bih0     = (const float*)d_in[7];
    const float* bhh0     = (const float*)d_in[8];
    const float* Wih1     = (const float*)d_in[9];
    const float* Whh1     = (const float*)d_in[10];
    const float* bih1     = (const float*)d_in[11];
    const float* bhh1     = (const float*)d_in[12];
    const int*  comb_a    = (const int*)d_in[13];
    const int*  comb_b    = (const int*)d_in[14];
    float* out = (float*)d_out;

    char* ws = (char*)d_ws;
    const size_t feat32_bytes = (size_t)NGRP * NWIN * 16 * FROW * 4;   // 83,361,792
    const size_t WH_BYTES = 3 * 2 * 12 * 64 * 8 * 2;                    // 73,728
    const size_t W0_BYTES = 7 * 12 * 64 * 8 * 2;                        // 86,016

    float* feat32 = (float*)ws;
    short* WHh = (short*)(ws + feat32_bytes);
    short* W0h = (short*)(ws + feat32_bytes + WH_BYTES);
    float* bf0 = (float*)(ws + feat32_bytes + WH_BYTES + W0_BYTES);
    float* accum = (float*)(ws + feat32_bytes + WH_BYTES + W0_BYTES + 1024);

    hipMemsetAsync(accum, 0, 2 * NG * sizeof(float), stream);
    stats_kernel<<<4096, 256, 0, stream>>>(data, comb_a, comb_b, feat32, accum);
    prep_kernel<<<64, 256, 0, stream>>>(Wih0, Whh0, Wih1, Whh1, bih0, accum,
                                        conv_w, bn_gamma, bn_beta, WHh, W0h, bf0);
    rec_kernel<<<NGRP, 512, 0, stream>>>(feat32, WHh, W0h, bf0,
                                         bhh0, bih1, bhh1, out);
}